// Round 17
// baseline (461.569 us; speedup 1.0000x reference)
//
#include <hip/hip_runtime.h>
#include <hip/hip_bf16.h>

#define D 128

__device__ __forceinline__ float bf2f(unsigned short u) {
  return __uint_as_float(((unsigned int)u) << 16);
}
__device__ __forceinline__ unsigned short f2bf(float f) {
  unsigned int x = __float_as_uint(f);
  x += 0x7fff + ((x >> 16) & 1);
  return (unsigned short)(x >> 16);
}

// flags: [0..4]=float tensor is-bf16 (emb,W1,b1,W2,b2), [5]=ints-int64

__global__ void k_detect_f5(const unsigned short* __restrict__ t0, int n0,
                            const unsigned short* __restrict__ t1, int n1,
                            const unsigned short* __restrict__ t2, int n2,
                            const unsigned short* __restrict__ t3, int n3,
                            const unsigned short* __restrict__ t4, int n4,
                            int* __restrict__ flag) {
  const unsigned short* tabs[5] = {t0, t1, t2, t3, t4};
  int ns[5] = {n0, n1, n2, n3, n4};
  int b = blockIdx.x;
  const unsigned short* u16 = tabs[b];
  int n = ns[b];
  __shared__ int cnt;
  int K = n / 2 < 256 ? n / 2 : 256;
  if (threadIdx.x == 0) cnt = 0;
  __syncthreads();
  if (threadIdx.x < K) {
    unsigned short u = u16[threadIdx.x * 2];
    int e = (u >> 7) & 0xFF;
    if (u == 0 || (e >= 100 && e <= 140)) atomicAdd(&cnt, 1);
  }
  __syncthreads();
  if (threadIdx.x == 0) flag[b] = (cnt * 2 >= K) ? 1 : 0;
}

__global__ void k_detect_i(const unsigned int* __restrict__ ei32,
                           int* __restrict__ flagSlot) {
  __shared__ int z;
  if (threadIdx.x == 0) z = 0;
  __syncthreads();
  if (ei32[threadIdx.x * 2 + 1] == 0u) atomicAdd(&z, 1);
  __syncthreads();
  if (threadIdx.x == 0) *flagSlot = (z >= 60) ? 1 : 0;
}

__global__ void k_conv(const void* __restrict__ src, float* __restrict__ dst,
                       int n, const int* __restrict__ flagSlot) {
  int i = blockIdx.x * blockDim.x + threadIdx.x;
  if (i >= n) return;
  if (*flagSlot) dst[i] = bf2f(((const unsigned short*)src)[i]);
  else           dst[i] = ((const float*)src)[i];
}

__global__ void k_conv_params(const void* __restrict__ W1, const void* __restrict__ b1,
                              const void* __restrict__ W2, const void* __restrict__ b2,
                              float* __restrict__ W1f, float* __restrict__ b1f,
                              float* __restrict__ W2f, float* __restrict__ b2f,
                              const int* __restrict__ flag) {
  int i = blockIdx.x * blockDim.x + threadIdx.x;
  const int S = D * D;
  const void* src; float* dst; int j; const int* fs;
  if (i < S)                { src = W1; dst = W1f; j = i;            fs = flag + 1; }
  else if (i < S + D)       { src = b1; dst = b1f; j = i - S;        fs = flag + 2; }
  else if (i < 2 * S + D)   { src = W2; dst = W2f; j = i - S - D;    fs = flag + 3; }
  else if (i < 2 * S + 2*D) { src = b2; dst = b2f; j = i - 2*S - D;  fs = flag + 4; }
  else return;
  if (*fs) dst[j] = bf2f(((const unsigned short*)src)[j]);
  else     dst[j] = ((const float*)src)[j];
}

// fused int conversion with clamping (swap-guard removed: never fired)
__global__ void k_convi_all(const void* __restrict__ xr, const void* __restrict__ eir,
                            const void* __restrict__ br,
                            int* __restrict__ xs, int* __restrict__ srcs,
                            int* __restrict__ dsts, int* __restrict__ batchs,
                            int nn, int ne, int vocab, int ng,
                            const int* __restrict__ flag64) {
  long long i = (long long)blockIdx.x * blockDim.x + threadIdx.x;
  int is64 = *flag64;
  if (i < nn) {
    int v = is64 ? (int)((const long long*)xr)[i] : ((const int*)xr)[i];
    v = v < 0 ? 0 : (v > vocab - 1 ? vocab - 1 : v);
    xs[i] = v;
  } else if (i < (long long)nn + ne) {
    long long j = i - nn;
    int v = is64 ? (int)((const long long*)eir)[j] : ((const int*)eir)[j];
    v = v < 0 ? 0 : (v > nn - 1 ? nn - 1 : v);
    srcs[j] = v;
  } else if (i < (long long)nn + 2 * ne) {
    long long j = i - nn - ne;
    int v = is64 ? (int)((const long long*)eir)[ne + j] : ((const int*)eir)[ne + j];
    v = v < 0 ? 0 : (v > nn - 1 ? nn - 1 : v);
    dsts[j] = v;
  } else if (i < 2LL * nn + 2 * ne) {
    long long j = i - nn - 2 * ne;
    int v = is64 ? (int)((const long long*)br)[j] : ((const int*)br)[j];
    v = v < 0 ? 0 : (v > ng - 1 ? ng - 1 : v);
    batchs[j] = v;
  }
}

// ---------------- CSR build ------------------------------------------------
__global__ void k_count(const int* __restrict__ dstA, int* __restrict__ indeg,
                        int ne) {
  int e = blockIdx.x * blockDim.x + threadIdx.x;
  if (e < ne) atomicAdd(&indeg[dstA[e]], 1);
}

__global__ __launch_bounds__(1024) void k_scan1(const int* __restrict__ indeg,
                                                int* __restrict__ off,
                                                int* __restrict__ bsum, int nn) {
  int t = threadIdx.x;
  int idx = blockIdx.x * 1024 + t;
  int v = (idx < nn) ? indeg[idx] : 0;
  int lane = t & 63, wid = t >> 6;
  int inc = v;
  #pragma unroll
  for (int d = 1; d < 64; d <<= 1) {
    int u = __shfl_up(inc, d);
    if (lane >= d) inc += u;
  }
  __shared__ int ws[16];
  if (lane == 63) ws[wid] = inc;
  __syncthreads();
  if (wid == 0) {
    int wv = (lane < 16) ? ws[lane] : 0;
    #pragma unroll
    for (int d = 1; d < 16; d <<= 1) {
      int u = __shfl_up(wv, d);
      if (lane >= d) wv += u;
    }
    if (lane < 16) ws[lane] = wv;
  }
  __syncthreads();
  int base = wid ? ws[wid - 1] : 0;
  if (idx < nn) off[idx] = base + inc - v;
  if (t == 1023) bsum[blockIdx.x] = ws[15];
}

__global__ void k_scan2(int* __restrict__ bsum, int nb) {
  if (blockIdx.x == 0 && threadIdx.x == 0) {
    int run = 0;
    for (int i = 0; i < nb; ++i) { int s = bsum[i]; bsum[i] = run; run += s; }
  }
}

__global__ void k_scan3(int* __restrict__ off, int* __restrict__ cursor,
                        float* __restrict__ dis, const int* __restrict__ indeg,
                        const int* __restrict__ bsum, int nn) {
  int idx = blockIdx.x * blockDim.x + threadIdx.x;
  if (idx >= nn) return;
  int o = off[idx] + bsum[idx >> 10];
  off[idx] = o;
  cursor[idx] = o;
  dis[idx] = rsqrtf((float)indeg[idx] + 1.0f);  // +1 self-loop
}

// fill packed CSR: csrA=(x[src], norm) for layer1, csrB=(src, norm) for layer2
__global__ void k_fill(const int* __restrict__ srcA, const int* __restrict__ dstA,
                       const int* __restrict__ xs, const float* __restrict__ dis,
                       int* __restrict__ cursor,
                       int2* __restrict__ csrA, int2* __restrict__ csrB, int ne) {
  int e = blockIdx.x * blockDim.x + threadIdx.x;
  if (e >= ne) return;
  int d = dstA[e], s = srcA[e];
  float w = dis[s] * dis[d];
  int pp = atomicAdd(&cursor[d], 1);
  csrA[pp] = make_int2(xs[s], __float_as_int(w));
  csrB[pp] = make_int2(s, __float_as_int(w));
}

// ---------------- G = emb @ W1 --------------------------------------------
__global__ void k_gemm_dumb(const float* __restrict__ A,
                            const float* __restrict__ W,
                            float* __restrict__ OUT, int rows) {
  int idx = blockIdx.x * blockDim.x + threadIdx.x;
  if (idx >= rows * D) return;
  int r = idx >> 7, c = idx & 127;
  const float* a = A + (size_t)r * D;
  float acc = 0.f;
  for (int k = 0; k < D; ++k) acc += a[k] * W[k * D + c];
  OUT[idx] = acc;
}

// ---- layer1: H1[n]=relu(dn^2*G[x[n]] + sum w*G[xsrc] + b1) -> bf16 -------
// 32 lanes/node (float4 slices), 2 nodes/wave, unroll-2 edge loop
__global__ __launch_bounds__(256) void k_aggrelu(const int* __restrict__ x,
                                                 const float* __restrict__ G,
                                                 const float* __restrict__ b1,
                                                 const int* __restrict__ off,
                                                 const int* __restrict__ indeg,
                                                 const float* __restrict__ dis,
                                                 const int2* __restrict__ csrA,
                                                 unsigned short* __restrict__ H1,
                                                 int nn) {
  int gid = blockIdx.x * blockDim.x + threadIdx.x;
  int n = gid >> 5;
  if (n >= nn) return;
  int lane = threadIdx.x & 31;
  float dn = dis[n];
  float sn = dn * dn;
  float4 g0 = ((const float4*)(G + (size_t)x[n] * D))[lane];
  float ax = sn * g0.x, ay = sn * g0.y, az = sn * g0.z, aw = sn * g0.w;
  int s0 = off[n], m = indeg[n];
  int j = 0;
  for (; j + 1 < m; j += 2) {
    int2 e0 = csrA[s0 + j];
    int2 e1 = csrA[s0 + j + 1];
    float w0 = __int_as_float(e0.y);
    float w1 = __int_as_float(e1.y);
    float4 gA = ((const float4*)(G + (size_t)e0.x * D))[lane];
    float4 gB = ((const float4*)(G + (size_t)e1.x * D))[lane];
    ax += w0 * gA.x + w1 * gB.x;
    ay += w0 * gA.y + w1 * gB.y;
    az += w0 * gA.z + w1 * gB.z;
    aw += w0 * gA.w + w1 * gB.w;
  }
  if (j < m) {
    int2 e0 = csrA[s0 + j];
    float w0 = __int_as_float(e0.y);
    float4 gA = ((const float4*)(G + (size_t)e0.x * D))[lane];
    ax += w0 * gA.x; ay += w0 * gA.y; az += w0 * gA.z; aw += w0 * gA.w;
  }
  float4 bb = ((const float4*)b1)[lane];
  ushort4 o;
  o.x = f2bf(fmaxf(ax + bb.x, 0.f));
  o.y = f2bf(fmaxf(ay + bb.y, 0.f));
  o.z = f2bf(fmaxf(az + bb.z, 0.f));
  o.w = f2bf(fmaxf(aw + bb.w, 0.f));
  ((ushort4*)(H1 + (size_t)n * D))[lane] = o;
}

// ---- fused layer2 + mean-pool + output GEMM: one block (256 thr) per graph
// thread t: col c=t&127, node-parity half=t>>7 (wave-uniform). batch sorted.
__global__ __launch_bounds__(256) void k_agg2poolout(
    const unsigned short* __restrict__ H1, const int* __restrict__ off,
    const int* __restrict__ indeg, const float* __restrict__ dis,
    const int2* __restrict__ csrB, const int* __restrict__ batch,
    const float* __restrict__ W2, const float* __restrict__ b2,
    float* __restrict__ Out, int nn) {
  int g = blockIdx.x;
  int t = threadIdx.x;
  int c = t & 127, half = t >> 7;
  // node range [s,e) of graph g
  int lo = 0, hi = nn;
  while (lo < hi) { int m = (lo + hi) >> 1; if (batch[m] < g) lo = m + 1; else hi = m; }
  int s = lo;
  hi = nn;
  while (lo < hi) { int m = (lo + hi) >> 1; if (batch[m] < g + 1) lo = m + 1; else hi = m; }
  int e = lo;
  float acc = 0.f;
  for (int n = s + half; n < e; n += 2) {
    float dn = dis[n];
    float v = dn * dn * bf2f(H1[(size_t)n * D + c]);
    int s0 = off[n], m = indeg[n];
    int j = 0;
    for (; j + 1 < m; j += 2) {
      int2 e0 = csrB[s0 + j];
      int2 e1 = csrB[s0 + j + 1];
      float w0 = __int_as_float(e0.y);
      float w1 = __int_as_float(e1.y);
      float h0 = bf2f(H1[(size_t)e0.x * D + c]);
      float h1 = bf2f(H1[(size_t)e1.x * D + c]);
      v += w0 * h0 + w1 * h1;
    }
    if (j < m) {
      int2 e0 = csrB[s0 + j];
      v += __int_as_float(e0.y) * bf2f(H1[(size_t)e0.x * D + c]);
    }
    acc += v;
  }
  __shared__ float red[256];
  red[t] = acc;
  __syncthreads();
  if (t < 128) red[t] += red[t + 128];
  __syncthreads();
  int mcnt = e - s;
  float inv = (mcnt > 0) ? (1.0f / (float)mcnt) : 0.0f;
  __shared__ float Pr[128];
  if (t < 128) Pr[t] = red[t] * inv;
  __syncthreads();
  if (t < 128) {
    float o = 0.f;
    for (int k = 0; k < 128; ++k) o += Pr[k] * W2[k * D + c];
    if (mcnt > 0) o += b2[c];
    Out[(size_t)g * D + c] = o;
  }
}

extern "C" void kernel_launch(void* const* d_in, const int* in_sizes, int n_in,
                              void* d_out, int out_size, void* d_ws, size_t ws_size,
                              hipStream_t stream) {
  const void* xr = d_in[0];
  const void* eir = d_in[1];
  const void* batchr = d_in[2];
  const void* emb = d_in[3];
  const void* W1 = d_in[4];
  const void* b1 = d_in[5];
  const void* W2 = d_in[6];
  const void* b2 = d_in[7];
  float* out = (float*)d_out;

  const int nn = in_sizes[0];
  const int ne = in_sizes[1] / 2;
  const int vocab = in_sizes[3] / D;
  const int ng = out_size / D;
  const int nb = (nn + 1023) / 1024;

  char* p = (char*)d_ws;
  auto alloc = [&](size_t bytes) -> char* {
    char* r = p;
    p += (bytes + 511) & ~(size_t)511;
    return r;
  };
  int* flag = (int*)alloc(512);
  int* xs = (int*)alloc((size_t)nn * 4);
  int* srcs = (int*)alloc((size_t)ne * 4);
  int* dsts = (int*)alloc((size_t)ne * 4);
  int* batchs = (int*)alloc((size_t)nn * 4);
  int* indeg = (int*)alloc((size_t)nn * 4);
  int* off = (int*)alloc((size_t)nn * 4);
  int* cursor = (int*)alloc((size_t)nn * 4);
  float* dis = (float*)alloc((size_t)nn * 4);
  int* bsum = (int*)alloc((size_t)nb * 4);
  int2* csrA = (int2*)alloc((size_t)ne * 8);
  int2* csrB = (int2*)alloc((size_t)ne * 8);
  float* embf = (float*)alloc((size_t)vocab * D * 4);
  float* W1f = (float*)alloc((size_t)D * D * 4);
  float* b1f = (float*)alloc((size_t)D * 4);
  float* W2f = (float*)alloc((size_t)D * D * 4);
  float* b2f = (float*)alloc((size_t)D * 4);
  float* G = (float*)alloc((size_t)vocab * D * 4);
  unsigned short* H1 = (unsigned short*)alloc((size_t)nn * D * 2);

  hipMemsetAsync(flag, 0, 512, stream);

  k_detect_f5<<<5, 256, 0, stream>>>(
      (const unsigned short*)emb, vocab * D,
      (const unsigned short*)W1, D * D,
      (const unsigned short*)b1, D,
      (const unsigned short*)W2, D * D,
      (const unsigned short*)b2, D, flag);
  k_detect_i<<<1, 64, 0, stream>>>((const unsigned int*)eir, flag + 5);

  k_conv<<<(vocab * D + 255) / 256, 256, 0, stream>>>(emb, embf, vocab * D, flag + 0);
  k_conv_params<<<(2 * D * D + 2 * D + 255) / 256, 256, 0, stream>>>(
      W1, b1, W2, b2, W1f, b1f, W2f, b2f, flag);

  {
    long long tot = 2LL * nn + 2LL * ne;
    k_convi_all<<<(int)((tot + 255) / 256), 256, 0, stream>>>(
        xr, eir, batchr, xs, srcs, dsts, batchs, nn, ne, vocab, ng, flag + 5);
  }

  hipMemsetAsync(indeg, 0, (size_t)nn * 4, stream);

  k_count<<<(ne + 255) / 256, 256, 0, stream>>>(dsts, indeg, ne);
  k_scan1<<<nb, 1024, 0, stream>>>(indeg, off, bsum, nn);
  k_scan2<<<1, 64, 0, stream>>>(bsum, nb);
  k_scan3<<<(nn + 255) / 256, 256, 0, stream>>>(off, cursor, dis, indeg, bsum, nn);
  k_fill<<<(ne + 255) / 256, 256, 0, stream>>>(srcs, dsts, xs, dis, cursor,
                                               csrA, csrB, ne);

  k_gemm_dumb<<<(vocab * D + 255) / 256, 256, 0, stream>>>(embf, W1f, G, vocab);

  // layer 1 -> H1 bf16
  {
    long long thr = (long long)nn * 32;
    k_aggrelu<<<(int)((thr + 255) / 256), 256, 0, stream>>>(xs, G, b1f, off, indeg,
                                                            dis, csrA, H1, nn);
  }
  // fused layer2 + pool + out
  k_agg2poolout<<<ng, 256, 0, stream>>>(H1, off, indeg, dis, csrB, batchs,
                                        W2f, b2f, out, nn);
}

// Round 18
// 319.535 us; speedup vs baseline: 1.4445x; 1.4445x over previous
//
#include <hip/hip_runtime.h>
#include <hip/hip_bf16.h>

#define D 128

__device__ __forceinline__ float bf2f(unsigned short u) {
  return __uint_as_float(((unsigned int)u) << 16);
}
__device__ __forceinline__ unsigned short f2bf(float f) {
  unsigned int x = __float_as_uint(f);
  x += 0x7fff + ((x >> 16) & 1);
  return (unsigned short)(x >> 16);
}

// flags: [0..4]=float tensor is-bf16 (emb,W1,b1,W2,b2), [5]=ints-int64

__global__ void k_detect_f5(const unsigned short* __restrict__ t0, int n0,
                            const unsigned short* __restrict__ t1, int n1,
                            const unsigned short* __restrict__ t2, int n2,
                            const unsigned short* __restrict__ t3, int n3,
                            const unsigned short* __restrict__ t4, int n4,
                            int* __restrict__ flag) {
  const unsigned short* tabs[5] = {t0, t1, t2, t3, t4};
  int ns[5] = {n0, n1, n2, n3, n4};
  int b = blockIdx.x;
  const unsigned short* u16 = tabs[b];
  int n = ns[b];
  __shared__ int cnt;
  int K = n / 2 < 256 ? n / 2 : 256;
  if (threadIdx.x == 0) cnt = 0;
  __syncthreads();
  if (threadIdx.x < K) {
    unsigned short u = u16[threadIdx.x * 2];
    int e = (u >> 7) & 0xFF;
    if (u == 0 || (e >= 100 && e <= 140)) atomicAdd(&cnt, 1);
  }
  __syncthreads();
  if (threadIdx.x == 0) flag[b] = (cnt * 2 >= K) ? 1 : 0;
}

__global__ void k_detect_i(const unsigned int* __restrict__ ei32,
                           int* __restrict__ flagSlot) {
  __shared__ int z;
  if (threadIdx.x == 0) z = 0;
  __syncthreads();
  if (ei32[threadIdx.x * 2 + 1] == 0u) atomicAdd(&z, 1);
  __syncthreads();
  if (threadIdx.x == 0) *flagSlot = (z >= 60) ? 1 : 0;
}

__global__ void k_conv(const void* __restrict__ src, float* __restrict__ dst,
                       int n, const int* __restrict__ flagSlot) {
  int i = blockIdx.x * blockDim.x + threadIdx.x;
  if (i >= n) return;
  if (*flagSlot) dst[i] = bf2f(((const unsigned short*)src)[i]);
  else           dst[i] = ((const float*)src)[i];
}

__global__ void k_conv_params(const void* __restrict__ W1, const void* __restrict__ b1,
                              const void* __restrict__ W2, const void* __restrict__ b2,
                              float* __restrict__ W1f, float* __restrict__ b1f,
                              float* __restrict__ W2f, float* __restrict__ b2f,
                              const int* __restrict__ flag) {
  int i = blockIdx.x * blockDim.x + threadIdx.x;
  const int S = D * D;
  const void* src; float* dst; int j; const int* fs;
  if (i < S)                { src = W1; dst = W1f; j = i;            fs = flag + 1; }
  else if (i < S + D)       { src = b1; dst = b1f; j = i - S;        fs = flag + 2; }
  else if (i < 2 * S + D)   { src = W2; dst = W2f; j = i - S - D;    fs = flag + 3; }
  else if (i < 2 * S + 2*D) { src = b2; dst = b2f; j = i - 2*S - D;  fs = flag + 4; }
  else return;
  if (*fs) dst[j] = bf2f(((const unsigned short*)src)[j]);
  else     dst[j] = ((const float*)src)[j];
}

__global__ void k_convi_all(const void* __restrict__ xr, const void* __restrict__ eir,
                            const void* __restrict__ br,
                            int* __restrict__ xs, int* __restrict__ srcs,
                            int* __restrict__ dsts, int* __restrict__ batchs,
                            int nn, int ne, int vocab, int ng,
                            const int* __restrict__ flag64) {
  long long i = (long long)blockIdx.x * blockDim.x + threadIdx.x;
  int is64 = *flag64;
  if (i < nn) {
    int v = is64 ? (int)((const long long*)xr)[i] : ((const int*)xr)[i];
    v = v < 0 ? 0 : (v > vocab - 1 ? vocab - 1 : v);
    xs[i] = v;
  } else if (i < (long long)nn + ne) {
    long long j = i - nn;
    int v = is64 ? (int)((const long long*)eir)[j] : ((const int*)eir)[j];
    v = v < 0 ? 0 : (v > nn - 1 ? nn - 1 : v);
    srcs[j] = v;
  } else if (i < (long long)nn + 2 * ne) {
    long long j = i - nn - ne;
    int v = is64 ? (int)((const long long*)eir)[ne + j] : ((const int*)eir)[ne + j];
    v = v < 0 ? 0 : (v > nn - 1 ? nn - 1 : v);
    dsts[j] = v;
  } else if (i < 2LL * nn + 2 * ne) {
    long long j = i - nn - 2 * ne;
    int v = is64 ? (int)((const long long*)br)[j] : ((const int*)br)[j];
    v = v < 0 ? 0 : (v > ng - 1 ? ng - 1 : v);
    batchs[j] = v;
  }
}

// ---------------- CSR build ------------------------------------------------
__global__ void k_count(const int* __restrict__ dstA, int* __restrict__ indeg,
                        int ne) {
  int e = blockIdx.x * blockDim.x + threadIdx.x;
  if (e < ne) atomicAdd(&indeg[dstA[e]], 1);
}

__global__ __launch_bounds__(1024) void k_scan1(const int* __restrict__ indeg,
                                                int* __restrict__ off,
                                                int* __restrict__ bsum, int nn) {
  int t = threadIdx.x;
  int idx = blockIdx.x * 1024 + t;
  int v = (idx < nn) ? indeg[idx] : 0;
  int lane = t & 63, wid = t >> 6;
  int inc = v;
  #pragma unroll
  for (int d = 1; d < 64; d <<= 1) {
    int u = __shfl_up(inc, d);
    if (lane >= d) inc += u;
  }
  __shared__ int ws[16];
  if (lane == 63) ws[wid] = inc;
  __syncthreads();
  if (wid == 0) {
    int wv = (lane < 16) ? ws[lane] : 0;
    #pragma unroll
    for (int d = 1; d < 16; d <<= 1) {
      int u = __shfl_up(wv, d);
      if (lane >= d) wv += u;
    }
    if (lane < 16) ws[lane] = wv;
  }
  __syncthreads();
  int base = wid ? ws[wid - 1] : 0;
  if (idx < nn) off[idx] = base + inc - v;
  if (t == 1023) bsum[blockIdx.x] = ws[15];
}

__global__ void k_scan2(int* __restrict__ bsum, int nb) {
  if (blockIdx.x == 0 && threadIdx.x == 0) {
    int run = 0;
    for (int i = 0; i < nb; ++i) { int s = bsum[i]; bsum[i] = run; run += s; }
  }
}

__global__ void k_scan3(int* __restrict__ off, int* __restrict__ cursor,
                        float* __restrict__ dis, const int* __restrict__ indeg,
                        const int* __restrict__ bsum, int nn) {
  int idx = blockIdx.x * blockDim.x + threadIdx.x;
  if (idx >= nn) return;
  int o = off[idx] + bsum[idx >> 10];
  off[idx] = o;
  cursor[idx] = o;
  dis[idx] = rsqrtf((float)indeg[idx] + 1.0f);  // +1 self-loop
}

// fill packed CSR: csrA=(x[src], norm) for layer1, csrB=(src, norm) for layer2
__global__ void k_fill(const int* __restrict__ srcA, const int* __restrict__ dstA,
                       const int* __restrict__ xs, const float* __restrict__ dis,
                       int* __restrict__ cursor,
                       int2* __restrict__ csrA, int2* __restrict__ csrB, int ne) {
  int e = blockIdx.x * blockDim.x + threadIdx.x;
  if (e >= ne) return;
  int d = dstA[e], s = srcA[e];
  float w = dis[s] * dis[d];
  int pp = atomicAdd(&cursor[d], 1);
  csrA[pp] = make_int2(xs[s], __float_as_int(w));
  csrB[pp] = make_int2(s, __float_as_int(w));
}

// ---------------- G = emb @ W1 --------------------------------------------
__global__ void k_gemm_dumb(const float* __restrict__ A,
                            const float* __restrict__ W,
                            float* __restrict__ OUT, int rows) {
  int idx = blockIdx.x * blockDim.x + threadIdx.x;
  if (idx >= rows * D) return;
  int r = idx >> 7, c = idx & 127;
  const float* a = A + (size_t)r * D;
  float acc = 0.f;
  for (int k = 0; k < D; ++k) acc += a[k] * W[k * D + c];
  OUT[idx] = acc;
}

// ---- layer1: H1[n]=relu(dn^2*G[x[n]] + sum w*G[xsrc] + b1) -> bf16 -------
// 32 lanes/node (float4 slices), 2 nodes/wave, unroll-2 edge loop
__global__ __launch_bounds__(256) void k_aggrelu(const int* __restrict__ x,
                                                 const float* __restrict__ G,
                                                 const float* __restrict__ b1,
                                                 const int* __restrict__ off,
                                                 const int* __restrict__ indeg,
                                                 const float* __restrict__ dis,
                                                 const int2* __restrict__ csrA,
                                                 unsigned short* __restrict__ H1,
                                                 int nn) {
  int gid = blockIdx.x * blockDim.x + threadIdx.x;
  int n = gid >> 5;
  if (n >= nn) return;
  int lane = threadIdx.x & 31;
  float dn = dis[n];
  float sn = dn * dn;
  float4 g0 = ((const float4*)(G + (size_t)x[n] * D))[lane];
  float ax = sn * g0.x, ay = sn * g0.y, az = sn * g0.z, aw = sn * g0.w;
  int s0 = off[n], m = indeg[n];
  int j = 0;
  for (; j + 1 < m; j += 2) {
    int2 e0 = csrA[s0 + j];
    int2 e1 = csrA[s0 + j + 1];
    float w0 = __int_as_float(e0.y);
    float w1 = __int_as_float(e1.y);
    float4 gA = ((const float4*)(G + (size_t)e0.x * D))[lane];
    float4 gB = ((const float4*)(G + (size_t)e1.x * D))[lane];
    ax += w0 * gA.x + w1 * gB.x;
    ay += w0 * gA.y + w1 * gB.y;
    az += w0 * gA.z + w1 * gB.z;
    aw += w0 * gA.w + w1 * gB.w;
  }
  if (j < m) {
    int2 e0 = csrA[s0 + j];
    float w0 = __int_as_float(e0.y);
    float4 gA = ((const float4*)(G + (size_t)e0.x * D))[lane];
    ax += w0 * gA.x; ay += w0 * gA.y; az += w0 * gA.z; aw += w0 * gA.w;
  }
  float4 bb = ((const float4*)b1)[lane];
  ushort4 o;
  o.x = f2bf(fmaxf(ax + bb.x, 0.f));
  o.y = f2bf(fmaxf(ay + bb.y, 0.f));
  o.z = f2bf(fmaxf(az + bb.z, 0.f));
  o.w = f2bf(fmaxf(aw + bb.w, 0.f));
  ((ushort4*)(H1 + (size_t)n * D))[lane] = o;
}

// ---- layer2: AGG2[n] = dn^2*H1[n] + sum w*H1[s]; 32 lanes/node, ushort4 --
__global__ __launch_bounds__(256) void k_agg2(const unsigned short* __restrict__ H1,
                                              const int* __restrict__ off,
                                              const int* __restrict__ indeg,
                                              const float* __restrict__ dis,
                                              const int2* __restrict__ csrB,
                                              float* __restrict__ AGG2, int nn) {
  int gid = blockIdx.x * blockDim.x + threadIdx.x;
  int n = gid >> 5;
  if (n >= nn) return;
  int lane = threadIdx.x & 31;
  float dn = dis[n];
  float sn = dn * dn;
  ushort4 u0 = ((const ushort4*)(H1 + (size_t)n * D))[lane];
  float ax = sn * bf2f(u0.x), ay = sn * bf2f(u0.y);
  float az = sn * bf2f(u0.z), aw = sn * bf2f(u0.w);
  int s0 = off[n], m = indeg[n];
  int j = 0;
  for (; j + 1 < m; j += 2) {
    int2 e0 = csrB[s0 + j];
    int2 e1 = csrB[s0 + j + 1];
    float w0 = __int_as_float(e0.y);
    float w1 = __int_as_float(e1.y);
    ushort4 hA = ((const ushort4*)(H1 + (size_t)e0.x * D))[lane];
    ushort4 hB = ((const ushort4*)(H1 + (size_t)e1.x * D))[lane];
    ax += w0 * bf2f(hA.x) + w1 * bf2f(hB.x);
    ay += w0 * bf2f(hA.y) + w1 * bf2f(hB.y);
    az += w0 * bf2f(hA.z) + w1 * bf2f(hB.z);
    aw += w0 * bf2f(hA.w) + w1 * bf2f(hB.w);
  }
  if (j < m) {
    int2 e0 = csrB[s0 + j];
    float w0 = __int_as_float(e0.y);
    ushort4 hA = ((const ushort4*)(H1 + (size_t)e0.x * D))[lane];
    ax += w0 * bf2f(hA.x); ay += w0 * bf2f(hA.y);
    az += w0 * bf2f(hA.z); aw += w0 * bf2f(hA.w);
  }
  ((float4*)(AGG2 + (size_t)n * D))[lane] = make_float4(ax, ay, az, aw);
}

// ---- pool: P[g][c] = sum over node range (batch sorted); also cnt[g] -----
__global__ __launch_bounds__(128) void k_pool(const float* __restrict__ AGG2,
                                              const int* __restrict__ batch,
                                              float* __restrict__ P,
                                              int* __restrict__ cnt, int nn) {
  int g = blockIdx.x;
  int c = threadIdx.x;
  int lo = 0, hi = nn;
  while (lo < hi) { int m = (lo + hi) >> 1; if (batch[m] < g) lo = m + 1; else hi = m; }
  int s = lo;
  hi = nn;
  while (lo < hi) { int m = (lo + hi) >> 1; if (batch[m] < g + 1) lo = m + 1; else hi = m; }
  int e = lo;
  float sum = 0.f;
  for (int n = s; n < e; ++n) sum += AGG2[(size_t)n * D + c];
  P[(size_t)g * D + c] = sum;
  if (c == 0) cnt[g] = e - s;
}

// ---------------- out[g][c] = (P[g]/cnt[g]) @ W2 + b2, f32 out ------------
__global__ void k_out_dumb(const float* __restrict__ P,
                           const int* __restrict__ cnt,
                           const float* __restrict__ W2,
                           const float* __restrict__ b2,
                           float* __restrict__ Out, int ng) {
  int idx = blockIdx.x * blockDim.x + threadIdx.x;
  if (idx >= ng * D) return;
  int g = idx >> 7, c = idx & 127;
  int m = cnt[g];
  float inv = (m > 0) ? (1.0f / (float)m) : 0.0f;
  const float* pr = P + (size_t)g * D;
  float acc = 0.f;
  for (int k = 0; k < D; ++k) acc += pr[k] * W2[k * D + c];
  acc *= inv;
  if (m > 0) acc += b2[c];
  Out[idx] = acc;
}

extern "C" void kernel_launch(void* const* d_in, const int* in_sizes, int n_in,
                              void* d_out, int out_size, void* d_ws, size_t ws_size,
                              hipStream_t stream) {
  const void* xr = d_in[0];
  const void* eir = d_in[1];
  const void* batchr = d_in[2];
  const void* emb = d_in[3];
  const void* W1 = d_in[4];
  const void* b1 = d_in[5];
  const void* W2 = d_in[6];
  const void* b2 = d_in[7];
  float* out = (float*)d_out;

  const int nn = in_sizes[0];
  const int ne = in_sizes[1] / 2;
  const int vocab = in_sizes[3] / D;
  const int ng = out_size / D;
  const int nb = (nn + 1023) / 1024;

  char* p = (char*)d_ws;
  auto alloc = [&](size_t bytes) -> char* {
    char* r = p;
    p += (bytes + 511) & ~(size_t)511;
    return r;
  };
  int* flag = (int*)alloc(512);
  int* xs = (int*)alloc((size_t)nn * 4);
  int* srcs = (int*)alloc((size_t)ne * 4);
  int* dsts = (int*)alloc((size_t)ne * 4);
  int* batchs = (int*)alloc((size_t)nn * 4);
  int* indeg = (int*)alloc((size_t)nn * 4);
  int* off = (int*)alloc((size_t)nn * 4);
  int* cursor = (int*)alloc((size_t)nn * 4);
  float* dis = (float*)alloc((size_t)nn * 4);
  int* bsum = (int*)alloc((size_t)nb * 4);
  int* cnt = (int*)alloc((size_t)ng * 4);
  int2* csrA = (int2*)alloc((size_t)ne * 8);
  int2* csrB = (int2*)alloc((size_t)ne * 8);
  float* embf = (float*)alloc((size_t)vocab * D * 4);
  float* W1f = (float*)alloc((size_t)D * D * 4);
  float* b1f = (float*)alloc((size_t)D * 4);
  float* W2f = (float*)alloc((size_t)D * D * 4);
  float* b2f = (float*)alloc((size_t)D * 4);
  float* G = (float*)alloc((size_t)vocab * D * 4);
  unsigned short* H1 = (unsigned short*)alloc((size_t)nn * D * 2);
  float* AGG2 = (float*)alloc((size_t)nn * D * 4);
  float* P = (float*)alloc((size_t)ng * D * 4);

  hipMemsetAsync(flag, 0, 512, stream);

  k_detect_f5<<<5, 256, 0, stream>>>(
      (const unsigned short*)emb, vocab * D,
      (const unsigned short*)W1, D * D,
      (const unsigned short*)b1, D,
      (const unsigned short*)W2, D * D,
      (const unsigned short*)b2, D, flag);
  k_detect_i<<<1, 64, 0, stream>>>((const unsigned int*)eir, flag + 5);

  k_conv<<<(vocab * D + 255) / 256, 256, 0, stream>>>(emb, embf, vocab * D, flag + 0);
  k_conv_params<<<(2 * D * D + 2 * D + 255) / 256, 256, 0, stream>>>(
      W1, b1, W2, b2, W1f, b1f, W2f, b2f, flag);

  {
    long long tot = 2LL * nn + 2LL * ne;
    k_convi_all<<<(int)((tot + 255) / 256), 256, 0, stream>>>(
        xr, eir, batchr, xs, srcs, dsts, batchs, nn, ne, vocab, ng, flag + 5);
  }

  hipMemsetAsync(indeg, 0, (size_t)nn * 4, stream);

  k_count<<<(ne + 255) / 256, 256, 0, stream>>>(dsts, indeg, ne);
  k_scan1<<<nb, 1024, 0, stream>>>(indeg, off, bsum, nn);
  k_scan2<<<1, 64, 0, stream>>>(bsum, nb);
  k_scan3<<<(nn + 255) / 256, 256, 0, stream>>>(off, cursor, dis, indeg, bsum, nn);
  k_fill<<<(ne + 255) / 256, 256, 0, stream>>>(srcs, dsts, xs, dis, cursor,
                                               csrA, csrB, ne);

  k_gemm_dumb<<<(vocab * D + 255) / 256, 256, 0, stream>>>(embf, W1f, G, vocab);

  // layer 1 -> H1 bf16
  {
    long long thr = (long long)nn * 32;
    k_aggrelu<<<(int)((thr + 255) / 256), 256, 0, stream>>>(xs, G, b1f, off, indeg,
                                                            dis, csrA, H1, nn);
  }
  // layer 2 -> AGG2 f32 (full node-parallel)
  {
    long long thr = (long long)nn * 32;
    k_agg2<<<(int)((thr + 255) / 256), 256, 0, stream>>>(H1, off, indeg, dis,
                                                         csrB, AGG2, nn);
  }
  // pool + out
  k_pool<<<ng, 128, 0, stream>>>(AGG2, batchs, P, cnt, nn);
  k_out_dumb<<<(ng * D + 255) / 256, 256, 0, stream>>>(P, cnt, W2f, b2f, out, ng);
}

// Round 19
// 281.933 us; speedup vs baseline: 1.6372x; 1.1334x over previous
//
#include <hip/hip_runtime.h>
#include <hip/hip_bf16.h>

#define D 128
#define PCHUNK 64

__device__ __forceinline__ float bf2f(unsigned short u) {
  return __uint_as_float(((unsigned int)u) << 16);
}
__device__ __forceinline__ unsigned short f2bf(float f) {
  unsigned int x = __float_as_uint(f);
  x += 0x7fff + ((x >> 16) & 1);
  return (unsigned short)(x >> 16);
}

// flags: [0..4]=float tensor is-bf16 (emb,W1,b1,W2,b2), [5]=ints-int64

__global__ void k_detect_f5(const unsigned short* __restrict__ t0, int n0,
                            const unsigned short* __restrict__ t1, int n1,
                            const unsigned short* __restrict__ t2, int n2,
                            const unsigned short* __restrict__ t3, int n3,
                            const unsigned short* __restrict__ t4, int n4,
                            int* __restrict__ flag) {
  const unsigned short* tabs[5] = {t0, t1, t2, t3, t4};
  int ns[5] = {n0, n1, n2, n3, n4};
  int b = blockIdx.x;
  const unsigned short* u16 = tabs[b];
  int n = ns[b];
  __shared__ int cnt;
  int K = n / 2 < 256 ? n / 2 : 256;
  if (threadIdx.x == 0) cnt = 0;
  __syncthreads();
  if (threadIdx.x < K) {
    unsigned short u = u16[threadIdx.x * 2];
    int e = (u >> 7) & 0xFF;
    if (u == 0 || (e >= 100 && e <= 140)) atomicAdd(&cnt, 1);
  }
  __syncthreads();
  if (threadIdx.x == 0) flag[b] = (cnt * 2 >= K) ? 1 : 0;
}

__global__ void k_detect_i(const unsigned int* __restrict__ ei32,
                           int* __restrict__ flagSlot) {
  __shared__ int z;
  if (threadIdx.x == 0) z = 0;
  __syncthreads();
  if (ei32[threadIdx.x * 2 + 1] == 0u) atomicAdd(&z, 1);
  __syncthreads();
  if (threadIdx.x == 0) *flagSlot = (z >= 60) ? 1 : 0;
}

__global__ void k_conv(const void* __restrict__ src, float* __restrict__ dst,
                       int n, const int* __restrict__ flagSlot) {
  int i = blockIdx.x * blockDim.x + threadIdx.x;
  if (i >= n) return;
  if (*flagSlot) dst[i] = bf2f(((const unsigned short*)src)[i]);
  else           dst[i] = ((const float*)src)[i];
}

__global__ void k_conv_params(const void* __restrict__ W1, const void* __restrict__ b1,
                              const void* __restrict__ W2, const void* __restrict__ b2,
                              float* __restrict__ W1f, float* __restrict__ b1f,
                              float* __restrict__ W2f, float* __restrict__ b2f,
                              const int* __restrict__ flag) {
  int i = blockIdx.x * blockDim.x + threadIdx.x;
  const int S = D * D;
  const void* src; float* dst; int j; const int* fs;
  if (i < S)                { src = W1; dst = W1f; j = i;            fs = flag + 1; }
  else if (i < S + D)       { src = b1; dst = b1f; j = i - S;        fs = flag + 2; }
  else if (i < 2 * S + D)   { src = W2; dst = W2f; j = i - S - D;    fs = flag + 3; }
  else if (i < 2 * S + 2*D) { src = b2; dst = b2f; j = i - 2*S - D;  fs = flag + 4; }
  else return;
  if (*fs) dst[j] = bf2f(((const unsigned short*)src)[j]);
  else     dst[j] = ((const float*)src)[j];
}

__global__ void k_convi_all(const void* __restrict__ xr, const void* __restrict__ eir,
                            const void* __restrict__ br,
                            int* __restrict__ xs, int* __restrict__ srcs,
                            int* __restrict__ dsts, int* __restrict__ batchs,
                            int nn, int ne, int vocab, int ng,
                            const int* __restrict__ flag64) {
  long long i = (long long)blockIdx.x * blockDim.x + threadIdx.x;
  int is64 = *flag64;
  if (i < nn) {
    int v = is64 ? (int)((const long long*)xr)[i] : ((const int*)xr)[i];
    v = v < 0 ? 0 : (v > vocab - 1 ? vocab - 1 : v);
    xs[i] = v;
  } else if (i < (long long)nn + ne) {
    long long j = i - nn;
    int v = is64 ? (int)((const long long*)eir)[j] : ((const int*)eir)[j];
    v = v < 0 ? 0 : (v > nn - 1 ? nn - 1 : v);
    srcs[j] = v;
  } else if (i < (long long)nn + 2 * ne) {
    long long j = i - nn - ne;
    int v = is64 ? (int)((const long long*)eir)[ne + j] : ((const int*)eir)[ne + j];
    v = v < 0 ? 0 : (v > nn - 1 ? nn - 1 : v);
    dsts[j] = v;
  } else if (i < 2LL * nn + 2 * ne) {
    long long j = i - nn - 2 * ne;
    int v = is64 ? (int)((const long long*)br)[j] : ((const int*)br)[j];
    v = v < 0 ? 0 : (v > ng - 1 ? ng - 1 : v);
    batchs[j] = v;
  }
}

// ---------------- CSR build ------------------------------------------------
__global__ void k_count(const int* __restrict__ dstA, int* __restrict__ indeg,
                        int ne) {
  int e = blockIdx.x * blockDim.x + threadIdx.x;
  if (e < ne) atomicAdd(&indeg[dstA[e]], 1);
}

__global__ __launch_bounds__(1024) void k_scan1(const int* __restrict__ indeg,
                                                int* __restrict__ off,
                                                int* __restrict__ bsum, int nn) {
  int t = threadIdx.x;
  int idx = blockIdx.x * 1024 + t;
  int v = (idx < nn) ? indeg[idx] : 0;
  int lane = t & 63, wid = t >> 6;
  int inc = v;
  #pragma unroll
  for (int d = 1; d < 64; d <<= 1) {
    int u = __shfl_up(inc, d);
    if (lane >= d) inc += u;
  }
  __shared__ int ws[16];
  if (lane == 63) ws[wid] = inc;
  __syncthreads();
  if (wid == 0) {
    int wv = (lane < 16) ? ws[lane] : 0;
    #pragma unroll
    for (int d = 1; d < 16; d <<= 1) {
      int u = __shfl_up(wv, d);
      if (lane >= d) wv += u;
    }
    if (lane < 16) ws[lane] = wv;
  }
  __syncthreads();
  int base = wid ? ws[wid - 1] : 0;
  if (idx < nn) off[idx] = base + inc - v;
  if (t == 1023) bsum[blockIdx.x] = ws[15];
}

__global__ void k_scan2(int* __restrict__ bsum, int nb) {
  if (blockIdx.x == 0 && threadIdx.x == 0) {
    int run = 0;
    for (int i = 0; i < nb; ++i) { int s = bsum[i]; bsum[i] = run; run += s; }
  }
}

__global__ void k_scan3(int* __restrict__ off, int* __restrict__ cursor,
                        float* __restrict__ dis, const int* __restrict__ indeg,
                        const int* __restrict__ bsum, int nn) {
  int idx = blockIdx.x * blockDim.x + threadIdx.x;
  if (idx >= nn) return;
  int o = off[idx] + bsum[idx >> 10];
  off[idx] = o;
  cursor[idx] = o;
  dis[idx] = rsqrtf((float)indeg[idx] + 1.0f);  // +1 self-loop
}

__global__ void k_fill(const int* __restrict__ srcA, const int* __restrict__ dstA,
                       const int* __restrict__ xs, const float* __restrict__ dis,
                       int* __restrict__ cursor,
                       int2* __restrict__ csrA, int2* __restrict__ csrB, int ne) {
  int e = blockIdx.x * blockDim.x + threadIdx.x;
  if (e >= ne) return;
  int d = dstA[e], s = srcA[e];
  float w = dis[s] * dis[d];
  int pp = atomicAdd(&cursor[d], 1);
  csrA[pp] = make_int2(xs[s], __float_as_int(w));
  csrB[pp] = make_int2(s, __float_as_int(w));
}

// ---------------- G = emb @ W1 --------------------------------------------
__global__ void k_gemm_dumb(const float* __restrict__ A,
                            const float* __restrict__ W,
                            float* __restrict__ OUT, int rows) {
  int idx = blockIdx.x * blockDim.x + threadIdx.x;
  if (idx >= rows * D) return;
  int r = idx >> 7, c = idx & 127;
  const float* a = A + (size_t)r * D;
  float acc = 0.f;
  for (int k = 0; k < D; ++k) acc += a[k] * W[k * D + c];
  OUT[idx] = acc;
}

// ---- layer1: H1[n]=relu(dn^2*G[x[n]] + sum w*G[xsrc] + b1) -> bf16 -------
__global__ __launch_bounds__(256) void k_aggrelu(const int* __restrict__ x,
                                                 const float* __restrict__ G,
                                                 const float* __restrict__ b1,
                                                 const int* __restrict__ off,
                                                 const int* __restrict__ indeg,
                                                 const float* __restrict__ dis,
                                                 const int2* __restrict__ csrA,
                                                 unsigned short* __restrict__ H1,
                                                 int nn) {
  int gid = blockIdx.x * blockDim.x + threadIdx.x;
  int n = gid >> 5;
  if (n >= nn) return;
  int lane = threadIdx.x & 31;
  float dn = dis[n];
  float sn = dn * dn;
  float4 g0 = ((const float4*)(G + (size_t)x[n] * D))[lane];
  float ax = sn * g0.x, ay = sn * g0.y, az = sn * g0.z, aw = sn * g0.w;
  int s0 = off[n], m = indeg[n];
  int j = 0;
  for (; j + 1 < m; j += 2) {
    int2 e0 = csrA[s0 + j];
    int2 e1 = csrA[s0 + j + 1];
    float w0 = __int_as_float(e0.y);
    float w1 = __int_as_float(e1.y);
    float4 gA = ((const float4*)(G + (size_t)e0.x * D))[lane];
    float4 gB = ((const float4*)(G + (size_t)e1.x * D))[lane];
    ax += w0 * gA.x + w1 * gB.x;
    ay += w0 * gA.y + w1 * gB.y;
    az += w0 * gA.z + w1 * gB.z;
    aw += w0 * gA.w + w1 * gB.w;
  }
  if (j < m) {
    int2 e0 = csrA[s0 + j];
    float w0 = __int_as_float(e0.y);
    float4 gA = ((const float4*)(G + (size_t)e0.x * D))[lane];
    ax += w0 * gA.x; ay += w0 * gA.y; az += w0 * gA.z; aw += w0 * gA.w;
  }
  float4 bb = ((const float4*)b1)[lane];
  ushort4 o;
  o.x = f2bf(fmaxf(ax + bb.x, 0.f));
  o.y = f2bf(fmaxf(ay + bb.y, 0.f));
  o.z = f2bf(fmaxf(az + bb.z, 0.f));
  o.w = f2bf(fmaxf(aw + bb.w, 0.f));
  ((ushort4*)(H1 + (size_t)n * D))[lane] = o;
}

// ---- layer2: AGG2[n] = dn^2*H1[n] + sum w*H1[s]; 32 lanes/node, ushort4 --
__global__ __launch_bounds__(256) void k_agg2(const unsigned short* __restrict__ H1,
                                              const int* __restrict__ off,
                                              const int* __restrict__ indeg,
                                              const float* __restrict__ dis,
                                              const int2* __restrict__ csrB,
                                              float* __restrict__ AGG2, int nn) {
  int gid = blockIdx.x * blockDim.x + threadIdx.x;
  int n = gid >> 5;
  if (n >= nn) return;
  int lane = threadIdx.x & 31;
  float dn = dis[n];
  float sn = dn * dn;
  ushort4 u0 = ((const ushort4*)(H1 + (size_t)n * D))[lane];
  float ax = sn * bf2f(u0.x), ay = sn * bf2f(u0.y);
  float az = sn * bf2f(u0.z), aw = sn * bf2f(u0.w);
  int s0 = off[n], m = indeg[n];
  int j = 0;
  for (; j + 1 < m; j += 2) {
    int2 e0 = csrB[s0 + j];
    int2 e1 = csrB[s0 + j + 1];
    float w0 = __int_as_float(e0.y);
    float w1 = __int_as_float(e1.y);
    ushort4 hA = ((const ushort4*)(H1 + (size_t)e0.x * D))[lane];
    ushort4 hB = ((const ushort4*)(H1 + (size_t)e1.x * D))[lane];
    ax += w0 * bf2f(hA.x) + w1 * bf2f(hB.x);
    ay += w0 * bf2f(hA.y) + w1 * bf2f(hB.y);
    az += w0 * bf2f(hA.z) + w1 * bf2f(hB.z);
    aw += w0 * bf2f(hA.w) + w1 * bf2f(hB.w);
  }
  if (j < m) {
    int2 e0 = csrB[s0 + j];
    float w0 = __int_as_float(e0.y);
    ushort4 hA = ((const ushort4*)(H1 + (size_t)e0.x * D))[lane];
    ax += w0 * bf2f(hA.x); ay += w0 * bf2f(hA.y);
    az += w0 * bf2f(hA.z); aw += w0 * bf2f(hA.w);
  }
  ((float4*)(AGG2 + (size_t)n * D))[lane] = make_float4(ax, ay, az, aw);
}

// ---- pool: node-chunk parallel, segmented flush (batch sorted) -----------
__global__ __launch_bounds__(128) void k_pool2(const float* __restrict__ AGG2,
                                               const int* __restrict__ batch,
                                               float* __restrict__ P, int nn) {
  int c = threadIdx.x;
  int start = blockIdx.x * PCHUNK;
  if (start >= nn) return;
  int end = start + PCHUNK < nn ? start + PCHUNK : nn;
  int gcur = batch[start];
  float acc = 0.f;
  for (int n = start; n < end; ++n) {
    int g = batch[n];
    if (g != gcur) {
      atomicAdd(&P[(size_t)gcur * D + c], acc);
      acc = 0.f;
      gcur = g;
    }
    acc += AGG2[(size_t)n * D + c];
  }
  atomicAdd(&P[(size_t)gcur * D + c], acc);
}

// ---- cnt[g] from sorted batch via binary search --------------------------
__global__ void k_cnt2(const int* __restrict__ batch, int* __restrict__ cnt,
                       int nn, int ng) {
  int g = blockIdx.x * blockDim.x + threadIdx.x;
  if (g >= ng) return;
  int lo = 0, hi = nn;
  while (lo < hi) { int m = (lo + hi) >> 1; if (batch[m] < g) lo = m + 1; else hi = m; }
  int s = lo;
  hi = nn;
  while (lo < hi) { int m = (lo + hi) >> 1; if (batch[m] < g + 1) lo = m + 1; else hi = m; }
  cnt[g] = lo - s;
}

// ---------------- out[g][c] = (P[g]/cnt[g]) @ W2 + b2, f32 out ------------
__global__ void k_out_dumb(const float* __restrict__ P,
                           const int* __restrict__ cnt,
                           const float* __restrict__ W2,
                           const float* __restrict__ b2,
                           float* __restrict__ Out, int ng) {
  int idx = blockIdx.x * blockDim.x + threadIdx.x;
  if (idx >= ng * D) return;
  int g = idx >> 7, c = idx & 127;
  int m = cnt[g];
  float inv = (m > 0) ? (1.0f / (float)m) : 0.0f;
  const float* pr = P + (size_t)g * D;
  float acc = 0.f;
  for (int k = 0; k < D; ++k) acc += pr[k] * W2[k * D + c];
  acc *= inv;
  if (m > 0) acc += b2[c];
  Out[idx] = acc;
}

extern "C" void kernel_launch(void* const* d_in, const int* in_sizes, int n_in,
                              void* d_out, int out_size, void* d_ws, size_t ws_size,
                              hipStream_t stream) {
  const void* xr = d_in[0];
  const void* eir = d_in[1];
  const void* batchr = d_in[2];
  const void* emb = d_in[3];
  const void* W1 = d_in[4];
  const void* b1 = d_in[5];
  const void* W2 = d_in[6];
  const void* b2 = d_in[7];
  float* out = (float*)d_out;

  const int nn = in_sizes[0];
  const int ne = in_sizes[1] / 2;
  const int vocab = in_sizes[3] / D;
  const int ng = out_size / D;
  const int nb = (nn + 1023) / 1024;

  char* p = (char*)d_ws;
  auto alloc = [&](size_t bytes) -> char* {
    char* r = p;
    p += (bytes + 511) & ~(size_t)511;
    return r;
  };
  int* flag = (int*)alloc(512);
  int* xs = (int*)alloc((size_t)nn * 4);
  int* srcs = (int*)alloc((size_t)ne * 4);
  int* dsts = (int*)alloc((size_t)ne * 4);
  int* batchs = (int*)alloc((size_t)nn * 4);
  int* indeg = (int*)alloc((size_t)nn * 4);
  int* off = (int*)alloc((size_t)nn * 4);
  int* cursor = (int*)alloc((size_t)nn * 4);
  float* dis = (float*)alloc((size_t)nn * 4);
  int* bsum = (int*)alloc((size_t)nb * 4);
  int* cnt = (int*)alloc((size_t)ng * 4);
  int2* csrA = (int2*)alloc((size_t)ne * 8);
  int2* csrB = (int2*)alloc((size_t)ne * 8);
  float* embf = (float*)alloc((size_t)vocab * D * 4);
  float* W1f = (float*)alloc((size_t)D * D * 4);
  float* b1f = (float*)alloc((size_t)D * 4);
  float* W2f = (float*)alloc((size_t)D * D * 4);
  float* b2f = (float*)alloc((size_t)D * 4);
  float* G = (float*)alloc((size_t)vocab * D * 4);
  unsigned short* H1 = (unsigned short*)alloc((size_t)nn * D * 2);
  float* AGG2 = (float*)alloc((size_t)nn * D * 4);
  float* P = (float*)alloc((size_t)ng * D * 4);

  hipMemsetAsync(flag, 0, 512, stream);

  k_detect_f5<<<5, 256, 0, stream>>>(
      (const unsigned short*)emb, vocab * D,
      (const unsigned short*)W1, D * D,
      (const unsigned short*)b1, D,
      (const unsigned short*)W2, D * D,
      (const unsigned short*)b2, D, flag);
  k_detect_i<<<1, 64, 0, stream>>>((const unsigned int*)eir, flag + 5);

  k_conv<<<(vocab * D + 255) / 256, 256, 0, stream>>>(emb, embf, vocab * D, flag + 0);
  k_conv_params<<<(2 * D * D + 2 * D + 255) / 256, 256, 0, stream>>>(
      W1, b1, W2, b2, W1f, b1f, W2f, b2f, flag);

  {
    long long tot = 2LL * nn + 2LL * ne;
    k_convi_all<<<(int)((tot + 255) / 256), 256, 0, stream>>>(
        xr, eir, batchr, xs, srcs, dsts, batchs, nn, ne, vocab, ng, flag + 5);
  }

  hipMemsetAsync(indeg, 0, (size_t)nn * 4, stream);
  hipMemsetAsync(P, 0, (size_t)ng * D * 4, stream);

  k_count<<<(ne + 255) / 256, 256, 0, stream>>>(dsts, indeg, ne);
  k_scan1<<<nb, 1024, 0, stream>>>(indeg, off, bsum, nn);
  k_scan2<<<1, 64, 0, stream>>>(bsum, nb);
  k_scan3<<<(nn + 255) / 256, 256, 0, stream>>>(off, cursor, dis, indeg, bsum, nn);
  k_fill<<<(ne + 255) / 256, 256, 0, stream>>>(srcs, dsts, xs, dis, cursor,
                                               csrA, csrB, ne);

  k_gemm_dumb<<<(vocab * D + 255) / 256, 256, 0, stream>>>(embf, W1f, G, vocab);

  // layer 1 -> H1 bf16
  {
    long long thr = (long long)nn * 32;
    k_aggrelu<<<(int)((thr + 255) / 256), 256, 0, stream>>>(xs, G, b1f, off, indeg,
                                                            dis, csrA, H1, nn);
  }
  // layer 2 -> AGG2 f32
  {
    long long thr = (long long)nn * 32;
    k_agg2<<<(int)((thr + 255) / 256), 256, 0, stream>>>(H1, off, indeg, dis,
                                                         csrB, AGG2, nn);
  }
  // pool (node-chunk parallel) + cnt + out
  k_pool2<<<(nn + PCHUNK - 1) / PCHUNK, 128, 0, stream>>>(AGG2, batchs, P, nn);
  k_cnt2<<<(ng + 255) / 256, 256, 0, stream>>>(batchs, cnt, nn, ng);
  k_out_dumb<<<(ng * D + 255) / 256, 256, 0, stream>>>(P, cnt, W2f, b2f, out, ng);
}

// Round 20
// 277.305 us; speedup vs baseline: 1.6645x; 1.0167x over previous
//
#include <hip/hip_runtime.h>
#include <hip/hip_bf16.h>

#define D 128
#define PCHUNK 64

__device__ __forceinline__ float bf2f(unsigned short u) {
  return __uint_as_float(((unsigned int)u) << 16);
}
__device__ __forceinline__ unsigned short f2bf(float f) {
  unsigned int x = __float_as_uint(f);
  x += 0x7fff + ((x >> 16) & 1);
  return (unsigned short)(x >> 16);
}

// flags: [0..4]=float tensor is-bf16 (emb,W1,b1,W2,b2), [5]=ints-int64

__global__ void k_detect_f5(const unsigned short* __restrict__ t0, int n0,
                            const unsigned short* __restrict__ t1, int n1,
                            const unsigned short* __restrict__ t2, int n2,
                            const unsigned short* __restrict__ t3, int n3,
                            const unsigned short* __restrict__ t4, int n4,
                            int* __restrict__ flag) {
  const unsigned short* tabs[5] = {t0, t1, t2, t3, t4};
  int ns[5] = {n0, n1, n2, n3, n4};
  int b = blockIdx.x;
  const unsigned short* u16 = tabs[b];
  int n = ns[b];
  __shared__ int cnt;
  int K = n / 2 < 256 ? n / 2 : 256;
  if (threadIdx.x == 0) cnt = 0;
  __syncthreads();
  if (threadIdx.x < K) {
    unsigned short u = u16[threadIdx.x * 2];
    int e = (u >> 7) & 0xFF;
    if (u == 0 || (e >= 100 && e <= 140)) atomicAdd(&cnt, 1);
  }
  __syncthreads();
  if (threadIdx.x == 0) flag[b] = (cnt * 2 >= K) ? 1 : 0;
}

__global__ void k_detect_i(const unsigned int* __restrict__ ei32,
                           int* __restrict__ flagSlot) {
  __shared__ int z;
  if (threadIdx.x == 0) z = 0;
  __syncthreads();
  if (ei32[threadIdx.x * 2 + 1] == 0u) atomicAdd(&z, 1);
  __syncthreads();
  if (threadIdx.x == 0) *flagSlot = (z >= 60) ? 1 : 0;
}

__global__ void k_conv(const void* __restrict__ src, float* __restrict__ dst,
                       int n, const int* __restrict__ flagSlot) {
  int i = blockIdx.x * blockDim.x + threadIdx.x;
  if (i >= n) return;
  if (*flagSlot) dst[i] = bf2f(((const unsigned short*)src)[i]);
  else           dst[i] = ((const float*)src)[i];
}

__global__ void k_conv_params(const void* __restrict__ W1, const void* __restrict__ b1,
                              const void* __restrict__ W2, const void* __restrict__ b2,
                              float* __restrict__ W1f, float* __restrict__ b1f,
                              float* __restrict__ W2f, float* __restrict__ b2f,
                              const int* __restrict__ flag) {
  int i = blockIdx.x * blockDim.x + threadIdx.x;
  const int S = D * D;
  const void* src; float* dst; int j; const int* fs;
  if (i < S)                { src = W1; dst = W1f; j = i;            fs = flag + 1; }
  else if (i < S + D)       { src = b1; dst = b1f; j = i - S;        fs = flag + 2; }
  else if (i < 2 * S + D)   { src = W2; dst = W2f; j = i - S - D;    fs = flag + 3; }
  else if (i < 2 * S + 2*D) { src = b2; dst = b2f; j = i - 2*S - D;  fs = flag + 4; }
  else return;
  if (*fs) dst[j] = bf2f(((const unsigned short*)src)[j]);
  else     dst[j] = ((const float*)src)[j];
}

// fused int conversion; dst branch also counts in-degrees (indeg pre-zeroed)
__global__ void k_convi_all(const void* __restrict__ xr, const void* __restrict__ eir,
                            const void* __restrict__ br,
                            int* __restrict__ xs, int* __restrict__ srcs,
                            int* __restrict__ dsts, int* __restrict__ batchs,
                            int* __restrict__ indeg,
                            int nn, int ne, int vocab, int ng,
                            const int* __restrict__ flag64) {
  long long i = (long long)blockIdx.x * blockDim.x + threadIdx.x;
  int is64 = *flag64;
  if (i < nn) {
    int v = is64 ? (int)((const long long*)xr)[i] : ((const int*)xr)[i];
    v = v < 0 ? 0 : (v > vocab - 1 ? vocab - 1 : v);
    xs[i] = v;
  } else if (i < (long long)nn + ne) {
    long long j = i - nn;
    int v = is64 ? (int)((const long long*)eir)[j] : ((const int*)eir)[j];
    v = v < 0 ? 0 : (v > nn - 1 ? nn - 1 : v);
    srcs[j] = v;
  } else if (i < (long long)nn + 2 * ne) {
    long long j = i - nn - ne;
    int v = is64 ? (int)((const long long*)eir)[ne + j] : ((const int*)eir)[ne + j];
    v = v < 0 ? 0 : (v > nn - 1 ? nn - 1 : v);
    dsts[j] = v;
    atomicAdd(&indeg[v], 1);          // fused degree count
  } else if (i < 2LL * nn + 2 * ne) {
    long long j = i - nn - 2 * ne;
    int v = is64 ? (int)((const long long*)br)[j] : ((const int*)br)[j];
    v = v < 0 ? 0 : (v > ng - 1 ? ng - 1 : v);
    batchs[j] = v;
  }
}

// ---------------- CSR scan -------------------------------------------------
__global__ __launch_bounds__(1024) void k_scan1(const int* __restrict__ indeg,
                                                int* __restrict__ off,
                                                int* __restrict__ bsum, int nn) {
  int t = threadIdx.x;
  int idx = blockIdx.x * 1024 + t;
  int v = (idx < nn) ? indeg[idx] : 0;
  int lane = t & 63, wid = t >> 6;
  int inc = v;
  #pragma unroll
  for (int d = 1; d < 64; d <<= 1) {
    int u = __shfl_up(inc, d);
    if (lane >= d) inc += u;
  }
  __shared__ int ws[16];
  if (lane == 63) ws[wid] = inc;
  __syncthreads();
  if (wid == 0) {
    int wv = (lane < 16) ? ws[lane] : 0;
    #pragma unroll
    for (int d = 1; d < 16; d <<= 1) {
      int u = __shfl_up(wv, d);
      if (lane >= d) wv += u;
    }
    if (lane < 16) ws[lane] = wv;
  }
  __syncthreads();
  int base = wid ? ws[wid - 1] : 0;
  if (idx < nn) off[idx] = base + inc - v;
  if (t == 1023) bsum[blockIdx.x] = ws[15];
}

__global__ void k_scan2(int* __restrict__ bsum, int nb) {
  if (blockIdx.x == 0 && threadIdx.x == 0) {
    int run = 0;
    for (int i = 0; i < nb; ++i) { int s = bsum[i]; bsum[i] = run; run += s; }
  }
}

__global__ void k_scan3(int* __restrict__ off, int* __restrict__ cursor,
                        float* __restrict__ dis, const int* __restrict__ indeg,
                        const int* __restrict__ bsum, int nn) {
  int idx = blockIdx.x * blockDim.x + threadIdx.x;
  if (idx >= nn) return;
  int o = off[idx] + bsum[idx >> 10];
  off[idx] = o;
  cursor[idx] = o;
  dis[idx] = rsqrtf((float)indeg[idx] + 1.0f);  // +1 self-loop
}

__global__ void k_fill(const int* __restrict__ srcA, const int* __restrict__ dstA,
                       const int* __restrict__ xs, const float* __restrict__ dis,
                       int* __restrict__ cursor,
                       int2* __restrict__ csrA, int2* __restrict__ csrB, int ne) {
  int e = blockIdx.x * blockDim.x + threadIdx.x;
  if (e >= ne) return;
  int d = dstA[e], s = srcA[e];
  float w = dis[s] * dis[d];
  int pp = atomicAdd(&cursor[d], 1);
  csrA[pp] = make_int2(xs[s], __float_as_int(w));
  csrB[pp] = make_int2(s, __float_as_int(w));
}

// ---------------- G = emb @ W1 --------------------------------------------
__global__ void k_gemm_dumb(const float* __restrict__ A,
                            const float* __restrict__ W,
                            float* __restrict__ OUT, int rows) {
  int idx = blockIdx.x * blockDim.x + threadIdx.x;
  if (idx >= rows * D) return;
  int r = idx >> 7, c = idx & 127;
  const float* a = A + (size_t)r * D;
  float acc = 0.f;
  for (int k = 0; k < D; ++k) acc += a[k] * W[k * D + c];
  OUT[idx] = acc;
}

// ---- layer1: H1[n]=relu(dn^2*G[x[n]] + sum w*G[xsrc] + b1) -> bf16 -------
// 32 lanes/node; software-pipelined edge loop (csr prefetch overlaps G loads)
__global__ __launch_bounds__(256) void k_aggrelu(const int* __restrict__ x,
                                                 const float* __restrict__ G,
                                                 const float* __restrict__ b1,
                                                 const int* __restrict__ off,
                                                 const int* __restrict__ indeg,
                                                 const float* __restrict__ dis,
                                                 const int2* __restrict__ csrA,
                                                 unsigned short* __restrict__ H1,
                                                 int nn) {
  int gid = blockIdx.x * blockDim.x + threadIdx.x;
  int n = gid >> 5;
  if (n >= nn) return;
  int lane = threadIdx.x & 31;
  float dn = dis[n];
  float sn = dn * dn;
  float4 g0 = ((const float4*)(G + (size_t)x[n] * D))[lane];
  float ax = sn * g0.x, ay = sn * g0.y, az = sn * g0.z, aw = sn * g0.w;
  int s0 = off[n], m = indeg[n];
  if (m >= 2) {
    int2 c0 = csrA[s0], c1 = csrA[s0 + 1];
    int j = 0;
    for (; j + 3 < m; j += 2) {
      int2 n0 = csrA[s0 + j + 2];
      int2 n1 = csrA[s0 + j + 3];
      float w0 = __int_as_float(c0.y);
      float w1 = __int_as_float(c1.y);
      float4 gA = ((const float4*)(G + (size_t)c0.x * D))[lane];
      float4 gB = ((const float4*)(G + (size_t)c1.x * D))[lane];
      ax += w0 * gA.x + w1 * gB.x;
      ay += w0 * gA.y + w1 * gB.y;
      az += w0 * gA.z + w1 * gB.z;
      aw += w0 * gA.w + w1 * gB.w;
      c0 = n0; c1 = n1;
    }
    {
      float w0 = __int_as_float(c0.y);
      float w1 = __int_as_float(c1.y);
      float4 gA = ((const float4*)(G + (size_t)c0.x * D))[lane];
      float4 gB = ((const float4*)(G + (size_t)c1.x * D))[lane];
      ax += w0 * gA.x + w1 * gB.x;
      ay += w0 * gA.y + w1 * gB.y;
      az += w0 * gA.z + w1 * gB.z;
      aw += w0 * gA.w + w1 * gB.w;
    }
    if (j + 2 < m) {
      int2 e0 = csrA[s0 + j + 2];
      float w0 = __int_as_float(e0.y);
      float4 gA = ((const float4*)(G + (size_t)e0.x * D))[lane];
      ax += w0 * gA.x; ay += w0 * gA.y; az += w0 * gA.z; aw += w0 * gA.w;
    }
  } else if (m == 1) {
    int2 e0 = csrA[s0];
    float w0 = __int_as_float(e0.y);
    float4 gA = ((const float4*)(G + (size_t)e0.x * D))[lane];
    ax += w0 * gA.x; ay += w0 * gA.y; az += w0 * gA.z; aw += w0 * gA.w;
  }
  float4 bb = ((const float4*)b1)[lane];
  ushort4 o;
  o.x = f2bf(fmaxf(ax + bb.x, 0.f));
  o.y = f2bf(fmaxf(ay + bb.y, 0.f));
  o.z = f2bf(fmaxf(az + bb.z, 0.f));
  o.w = f2bf(fmaxf(aw + bb.w, 0.f));
  ((ushort4*)(H1 + (size_t)n * D))[lane] = o;
}

// ---- layer2: AGG2[n] = dn^2*H1[n] + sum w*H1[s]; pipelined like aggrelu --
__global__ __launch_bounds__(256) void k_agg2(const unsigned short* __restrict__ H1,
                                              const int* __restrict__ off,
                                              const int* __restrict__ indeg,
                                              const float* __restrict__ dis,
                                              const int2* __restrict__ csrB,
                                              float* __restrict__ AGG2, int nn) {
  int gid = blockIdx.x * blockDim.x + threadIdx.x;
  int n = gid >> 5;
  if (n >= nn) return;
  int lane = threadIdx.x & 31;
  float dn = dis[n];
  float sn = dn * dn;
  ushort4 u0 = ((const ushort4*)(H1 + (size_t)n * D))[lane];
  float ax = sn * bf2f(u0.x), ay = sn * bf2f(u0.y);
  float az = sn * bf2f(u0.z), aw = sn * bf2f(u0.w);
  int s0 = off[n], m = indeg[n];
  if (m >= 2) {
    int2 c0 = csrB[s0], c1 = csrB[s0 + 1];
    int j = 0;
    for (; j + 3 < m; j += 2) {
      int2 n0 = csrB[s0 + j + 2];
      int2 n1 = csrB[s0 + j + 3];
      float w0 = __int_as_float(c0.y);
      float w1 = __int_as_float(c1.y);
      ushort4 hA = ((const ushort4*)(H1 + (size_t)c0.x * D))[lane];
      ushort4 hB = ((const ushort4*)(H1 + (size_t)c1.x * D))[lane];
      ax += w0 * bf2f(hA.x) + w1 * bf2f(hB.x);
      ay += w0 * bf2f(hA.y) + w1 * bf2f(hB.y);
      az += w0 * bf2f(hA.z) + w1 * bf2f(hB.z);
      aw += w0 * bf2f(hA.w) + w1 * bf2f(hB.w);
      c0 = n0; c1 = n1;
    }
    {
      float w0 = __int_as_float(c0.y);
      float w1 = __int_as_float(c1.y);
      ushort4 hA = ((const ushort4*)(H1 + (size_t)c0.x * D))[lane];
      ushort4 hB = ((const ushort4*)(H1 + (size_t)c1.x * D))[lane];
      ax += w0 * bf2f(hA.x) + w1 * bf2f(hB.x);
      ay += w0 * bf2f(hA.y) + w1 * bf2f(hB.y);
      az += w0 * bf2f(hA.z) + w1 * bf2f(hB.z);
      aw += w0 * bf2f(hA.w) + w1 * bf2f(hB.w);
    }
    if (j + 2 < m) {
      int2 e0 = csrB[s0 + j + 2];
      float w0 = __int_as_float(e0.y);
      ushort4 hA = ((const ushort4*)(H1 + (size_t)e0.x * D))[lane];
      ax += w0 * bf2f(hA.x); ay += w0 * bf2f(hA.y);
      az += w0 * bf2f(hA.z); aw += w0 * bf2f(hA.w);
    }
  } else if (m == 1) {
    int2 e0 = csrB[s0];
    float w0 = __int_as_float(e0.y);
    ushort4 hA = ((const ushort4*)(H1 + (size_t)e0.x * D))[lane];
    ax += w0 * bf2f(hA.x); ay += w0 * bf2f(hA.y);
    az += w0 * bf2f(hA.z); aw += w0 * bf2f(hA.w);
  }
  ((float4*)(AGG2 + (size_t)n * D))[lane] = make_float4(ax, ay, az, aw);
}

// ---- pool: node-chunk parallel, segmented flush (batch sorted) -----------
__global__ __launch_bounds__(128) void k_pool2(const float* __restrict__ AGG2,
                                               const int* __restrict__ batch,
                                               float* __restrict__ P, int nn) {
  int c = threadIdx.x;
  int start = blockIdx.x * PCHUNK;
  if (start >= nn) return;
  int end = start + PCHUNK < nn ? start + PCHUNK : nn;
  int gcur = batch[start];
  float acc = 0.f;
  for (int n = start; n < end; ++n) {
    int g = batch[n];
    if (g != gcur) {
      atomicAdd(&P[(size_t)gcur * D + c], acc);
      acc = 0.f;
      gcur = g;
    }
    acc += AGG2[(size_t)n * D + c];
  }
  atomicAdd(&P[(size_t)gcur * D + c], acc);
}

__global__ void k_cnt2(const int* __restrict__ batch, int* __restrict__ cnt,
                       int nn, int ng) {
  int g = blockIdx.x * blockDim.x + threadIdx.x;
  if (g >= ng) return;
  int lo = 0, hi = nn;
  while (lo < hi) { int m = (lo + hi) >> 1; if (batch[m] < g) lo = m + 1; else hi = m; }
  int s = lo;
  hi = nn;
  while (lo < hi) { int m = (lo + hi) >> 1; if (batch[m] < g + 1) lo = m + 1; else hi = m; }
  cnt[g] = lo - s;
}

__global__ void k_out_dumb(const float* __restrict__ P,
                           const int* __restrict__ cnt,
                           const float* __restrict__ W2,
                           const float* __restrict__ b2,
                           float* __restrict__ Out, int ng) {
  int idx = blockIdx.x * blockDim.x + threadIdx.x;
  if (idx >= ng * D) return;
  int g = idx >> 7, c = idx & 127;
  int m = cnt[g];
  float inv = (m > 0) ? (1.0f / (float)m) : 0.0f;
  const float* pr = P + (size_t)g * D;
  float acc = 0.f;
  for (int k = 0; k < D; ++k) acc += pr[k] * W2[k * D + c];
  acc *= inv;
  if (m > 0) acc += b2[c];
  Out[idx] = acc;
}

extern "C" void kernel_launch(void* const* d_in, const int* in_sizes, int n_in,
                              void* d_out, int out_size, void* d_ws, size_t ws_size,
                              hipStream_t stream) {
  const void* xr = d_in[0];
  const void* eir = d_in[1];
  const void* batchr = d_in[2];
  const void* emb = d_in[3];
  const void* W1 = d_in[4];
  const void* b1 = d_in[5];
  const void* W2 = d_in[6];
  const void* b2 = d_in[7];
  float* out = (float*)d_out;

  const int nn = in_sizes[0];
  const int ne = in_sizes[1] / 2;
  const int vocab = in_sizes[3] / D;
  const int ng = out_size / D;
  const int nb = (nn + 1023) / 1024;

  char* p = (char*)d_ws;
  auto alloc = [&](size_t bytes) -> char* {
    char* r = p;
    p += (bytes + 511) & ~(size_t)511;
    return r;
  };
  int* flag = (int*)alloc(512);
  int* xs = (int*)alloc((size_t)nn * 4);
  int* srcs = (int*)alloc((size_t)ne * 4);
  int* dsts = (int*)alloc((size_t)ne * 4);
  int* batchs = (int*)alloc((size_t)nn * 4);
  int* indeg = (int*)alloc((size_t)nn * 4);
  int* off = (int*)alloc((size_t)nn * 4);
  int* cursor = (int*)alloc((size_t)nn * 4);
  float* dis = (float*)alloc((size_t)nn * 4);
  int* bsum = (int*)alloc((size_t)nb * 4);
  int* cnt = (int*)alloc((size_t)ng * 4);
  int2* csrA = (int2*)alloc((size_t)ne * 8);
  int2* csrB = (int2*)alloc((size_t)ne * 8);
  float* embf = (float*)alloc((size_t)vocab * D * 4);
  float* W1f = (float*)alloc((size_t)D * D * 4);
  float* b1f = (float*)alloc((size_t)D * 4);
  float* W2f = (float*)alloc((size_t)D * D * 4);
  float* b2f = (float*)alloc((size_t)D * 4);
  float* G = (float*)alloc((size_t)vocab * D * 4);
  unsigned short* H1 = (unsigned short*)alloc((size_t)nn * D * 2);
  float* AGG2 = (float*)alloc((size_t)nn * D * 4);
  float* P = (float*)alloc((size_t)ng * D * 4);

  hipMemsetAsync(flag, 0, 512, stream);
  hipMemsetAsync(indeg, 0, (size_t)nn * 4, stream);
  hipMemsetAsync(P, 0, (size_t)ng * D * 4, stream);

  k_detect_f5<<<5, 256, 0, stream>>>(
      (const unsigned short*)emb, vocab * D,
      (const unsigned short*)W1, D * D,
      (const unsigned short*)b1, D,
      (const unsigned short*)W2, D * D,
      (const unsigned short*)b2, D, flag);
  k_detect_i<<<1, 64, 0, stream>>>((const unsigned int*)eir, flag + 5);

  k_conv<<<(vocab * D + 255) / 256, 256, 0, stream>>>(emb, embf, vocab * D, flag + 0);
  k_conv_params<<<(2 * D * D + 2 * D + 255) / 256, 256, 0, stream>>>(
      W1, b1, W2, b2, W1f, b1f, W2f, b2f, flag);

  {
    long long tot = 2LL * nn + 2LL * ne;
    k_convi_all<<<(int)((tot + 255) / 256), 256, 0, stream>>>(
        xr, eir, batchr, xs, srcs, dsts, batchs, indeg, nn, ne, vocab, ng, flag + 5);
  }

  k_scan1<<<nb, 1024, 0, stream>>>(indeg, off, bsum, nn);
  k_scan2<<<1, 64, 0, stream>>>(bsum, nb);
  k_scan3<<<(nn + 255) / 256, 256, 0, stream>>>(off, cursor, dis, indeg, bsum, nn);
  k_fill<<<(ne + 255) / 256, 256, 0, stream>>>(srcs, dsts, xs, dis, cursor,
                                               csrA, csrB, ne);

  k_gemm_dumb<<<(vocab * D + 255) / 256, 256, 0, stream>>>(embf, W1f, G, vocab);

  {
    long long thr = (long long)nn * 32;
    k_aggrelu<<<(int)((thr + 255) / 256), 256, 0, stream>>>(xs, G, b1f, off, indeg,
                                                            dis, csrA, H1, nn);
  }
  {
    long long thr = (long long)nn * 32;
    k_agg2<<<(int)((thr + 255) / 256), 256, 0, stream>>>(H1, off, indeg, dis,
                                                         csrB, AGG2, nn);
  }
  k_pool2<<<(nn + PCHUNK - 1) / PCHUNK, 128, 0, stream>>>(AGG2, batchs, P, nn);
  k_cnt2<<<(ng + 255) / 256, 256, 0, stream>>>(batchs, cnt, nn, ng);
  k_out_dumb<<<(ng * D + 255) / 256, 256, 0, stream>>>(P, cnt, W2f, b2f, out, ng);
}

// Round 21
// 258.829 us; speedup vs baseline: 1.7833x; 1.0714x over previous
//
#include <hip/hip_runtime.h>
#include <hip/hip_bf16.h>
#include <hip/hip_fp16.h>

#define D 128

__device__ __forceinline__ float bf2f(unsigned short u) {
  return __uint_as_float(((unsigned int)u) << 16);
}
__device__ __forceinline__ unsigned short f2bf(float f) {
  unsigned int x = __float_as_uint(f);
  x += 0x7fff + ((x >> 16) & 1);
  return (unsigned short)(x >> 16);
}
__device__ __forceinline__ float h2f(unsigned short b) {
  return __half2float(__ushort_as_half(b));
}

// flags: [0..4]=float tensor is-bf16 (emb,W1,b1,W2,b2), [5]=ints-int64

__global__ void k_detect_f5(const unsigned short* __restrict__ t0, int n0,
                            const unsigned short* __restrict__ t1, int n1,
                            const unsigned short* __restrict__ t2, int n2,
                            const unsigned short* __restrict__ t3, int n3,
                            const unsigned short* __restrict__ t4, int n4,
                            int* __restrict__ flag) {
  const unsigned short* tabs[5] = {t0, t1, t2, t3, t4};
  int ns[5] = {n0, n1, n2, n3, n4};
  int b = blockIdx.x;
  const unsigned short* u16 = tabs[b];
  int n = ns[b];
  __shared__ int cnt;
  int K = n / 2 < 256 ? n / 2 : 256;
  if (threadIdx.x == 0) cnt = 0;
  __syncthreads();
  if (threadIdx.x < K) {
    unsigned short u = u16[threadIdx.x * 2];
    int e = (u >> 7) & 0xFF;
    if (u == 0 || (e >= 100 && e <= 140)) atomicAdd(&cnt, 1);
  }
  __syncthreads();
  if (threadIdx.x == 0) flag[b] = (cnt * 2 >= K) ? 1 : 0;
}

__global__ void k_detect_i(const unsigned int* __restrict__ ei32,
                           int* __restrict__ flagSlot) {
  __shared__ int z;
  if (threadIdx.x == 0) z = 0;
  __syncthreads();
  if (ei32[threadIdx.x * 2 + 1] == 0u) atomicAdd(&z, 1);
  __syncthreads();
  if (threadIdx.x == 0) *flagSlot = (z >= 60) ? 1 : 0;
}

__global__ void k_conv(const void* __restrict__ src, float* __restrict__ dst,
                       int n, const int* __restrict__ flagSlot) {
  int i = blockIdx.x * blockDim.x + threadIdx.x;
  if (i >= n) return;
  if (*flagSlot) dst[i] = bf2f(((const unsigned short*)src)[i]);
  else           dst[i] = ((const float*)src)[i];
}

__global__ void k_conv_params(const void* __restrict__ W1, const void* __restrict__ b1,
                              const void* __restrict__ W2, const void* __restrict__ b2,
                              float* __restrict__ W1f, float* __restrict__ b1f,
                              float* __restrict__ W2f, float* __restrict__ b2f,
                              const int* __restrict__ flag) {
  int i = blockIdx.x * blockDim.x + threadIdx.x;
  const int S = D * D;
  const void* src; float* dst; int j; const int* fs;
  if (i < S)                { src = W1; dst = W1f; j = i;            fs = flag + 1; }
  else if (i < S + D)       { src = b1; dst = b1f; j = i - S;        fs = flag + 2; }
  else if (i < 2 * S + D)   { src = W2; dst = W2f; j = i - S - D;    fs = flag + 3; }
  else if (i < 2 * S + 2*D) { src = b2; dst = b2f; j = i - 2*S - D;  fs = flag + 4; }
  else return;
  if (*fs) dst[j] = bf2f(((const unsigned short*)src)[j]);
  else     dst[j] = ((const float*)src)[j];
}

// fused int conversion; dst branch also counts in-degrees (indeg pre-zeroed)
__global__ void k_convi_all(const void* __restrict__ xr, const void* __restrict__ eir,
                            const void* __restrict__ br,
                            int* __restrict__ xs, int* __restrict__ srcs,
                            int* __restrict__ dsts, int* __restrict__ batchs,
                            int* __restrict__ indeg,
                            int nn, int ne, int vocab, int ng,
                            const int* __restrict__ flag64) {
  long long i = (long long)blockIdx.x * blockDim.x + threadIdx.x;
  int is64 = *flag64;
  if (i < nn) {
    int v = is64 ? (int)((const long long*)xr)[i] : ((const int*)xr)[i];
    v = v < 0 ? 0 : (v > vocab - 1 ? vocab - 1 : v);
    xs[i] = v;
  } else if (i < (long long)nn + ne) {
    long long j = i - nn;
    int v = is64 ? (int)((const long long*)eir)[j] : ((const int*)eir)[j];
    v = v < 0 ? 0 : (v > nn - 1 ? nn - 1 : v);
    srcs[j] = v;
  } else if (i < (long long)nn + 2 * ne) {
    long long j = i - nn - ne;
    int v = is64 ? (int)((const long long*)eir)[ne + j] : ((const int*)eir)[ne + j];
    v = v < 0 ? 0 : (v > nn - 1 ? nn - 1 : v);
    dsts[j] = v;
    atomicAdd(&indeg[v], 1);
  } else if (i < 2LL * nn + 2 * ne) {
    long long j = i - nn - 2 * ne;
    int v = is64 ? (int)((const long long*)br)[j] : ((const int*)br)[j];
    v = v < 0 ? 0 : (v > ng - 1 ? ng - 1 : v);
    batchs[j] = v;
  }
}

// ---------------- CSR scan -------------------------------------------------
__global__ __launch_bounds__(1024) void k_scan1(const int* __restrict__ indeg,
                                                int* __restrict__ off,
                                                int* __restrict__ bsum, int nn) {
  int t = threadIdx.x;
  int idx = blockIdx.x * 1024 + t;
  int v = (idx < nn) ? indeg[idx] : 0;
  int lane = t & 63, wid = t >> 6;
  int inc = v;
  #pragma unroll
  for (int d = 1; d < 64; d <<= 1) {
    int u = __shfl_up(inc, d);
    if (lane >= d) inc += u;
  }
  __shared__ int ws[16];
  if (lane == 63) ws[wid] = inc;
  __syncthreads();
  if (wid == 0) {
    int wv = (lane < 16) ? ws[lane] : 0;
    #pragma unroll
    for (int d = 1; d < 16; d <<= 1) {
      int u = __shfl_up(wv, d);
      if (lane >= d) wv += u;
    }
    if (lane < 16) ws[lane] = wv;
  }
  __syncthreads();
  int base = wid ? ws[wid - 1] : 0;
  if (idx < nn) off[idx] = base + inc - v;
  if (t == 1023) bsum[blockIdx.x] = ws[15];
}

__global__ void k_scan2(int* __restrict__ bsum, int nb) {
  if (blockIdx.x == 0 && threadIdx.x == 0) {
    int run = 0;
    for (int i = 0; i < nb; ++i) { int s = bsum[i]; bsum[i] = run; run += s; }
  }
}

__global__ void k_scan3(int* __restrict__ off, int* __restrict__ cursor,
                        float* __restrict__ dis, const int* __restrict__ indeg,
                        const int* __restrict__ bsum, int nn) {
  int idx = blockIdx.x * blockDim.x + threadIdx.x;
  if (idx >= nn) return;
  int o = off[idx] + bsum[idx >> 10];
  off[idx] = o;
  cursor[idx] = o;
  dis[idx] = rsqrtf((float)indeg[idx] + 1.0f);  // +1 self-loop
}

// fill packed CSR: csrA = x[src] | f16(dis[src])<<16 ; csrB = src
// (norm dis[s]*dis[d] factorizes: dn applied once per node in the agg kernels)
__global__ void k_fill(const int* __restrict__ srcA, const int* __restrict__ dstA,
                       const int* __restrict__ xs, const float* __restrict__ dis,
                       int* __restrict__ cursor,
                       unsigned int* __restrict__ csrA, int* __restrict__ csrB,
                       int ne) {
  int e = blockIdx.x * blockDim.x + threadIdx.x;
  if (e >= ne) return;
  int d = dstA[e], s = srcA[e];
  unsigned short hb = __half_as_ushort(__float2half_rn(dis[s]));
  unsigned int packed = (unsigned int)xs[s] | ((unsigned int)hb << 16);
  int pp = atomicAdd(&cursor[d], 1);
  csrA[pp] = packed;
  csrB[pp] = s;
}

// ---------------- G = emb @ W1 --------------------------------------------
__global__ void k_gemm_dumb(const float* __restrict__ A,
                            const float* __restrict__ W,
                            float* __restrict__ OUT, int rows) {
  int idx = blockIdx.x * blockDim.x + threadIdx.x;
  if (idx >= rows * D) return;
  int r = idx >> 7, c = idx & 127;
  const float* a = A + (size_t)r * D;
  float acc = 0.f;
  for (int k = 0; k < D; ++k) acc += a[k] * W[k * D + c];
  OUT[idx] = acc;
}

// ---- layer1: H1p[n] = dn * relu(dn*(dn*G[x[n]] + sum dis_s*G[x_s]) + b1) -
// 32 lanes/node, software-pipelined, 4 B packed csr entries
__global__ __launch_bounds__(256) void k_aggrelu(const int* __restrict__ x,
                                                 const float* __restrict__ G,
                                                 const float* __restrict__ b1,
                                                 const int* __restrict__ off,
                                                 const int* __restrict__ indeg,
                                                 const float* __restrict__ dis,
                                                 const unsigned int* __restrict__ csrA,
                                                 unsigned short* __restrict__ H1,
                                                 int nn) {
  int gid = blockIdx.x * blockDim.x + threadIdx.x;
  int n = gid >> 5;
  if (n >= nn) return;
  int lane = threadIdx.x & 31;
  float dn = dis[n];
  float4 g0 = ((const float4*)(G + (size_t)x[n] * D))[lane];
  float ax = dn * g0.x, ay = dn * g0.y, az = dn * g0.z, aw = dn * g0.w;
  int s0 = off[n], m = indeg[n];
  if (m >= 2) {
    unsigned int c0 = csrA[s0], c1 = csrA[s0 + 1];
    int j = 0;
    for (; j + 3 < m; j += 2) {
      unsigned int p0 = csrA[s0 + j + 2];
      unsigned int p1 = csrA[s0 + j + 3];
      float w0 = h2f((unsigned short)(c0 >> 16));
      float w1 = h2f((unsigned short)(c1 >> 16));
      float4 gA = ((const float4*)(G + (size_t)(c0 & 0xFFFF) * D))[lane];
      float4 gB = ((const float4*)(G + (size_t)(c1 & 0xFFFF) * D))[lane];
      ax += w0 * gA.x + w1 * gB.x;
      ay += w0 * gA.y + w1 * gB.y;
      az += w0 * gA.z + w1 * gB.z;
      aw += w0 * gA.w + w1 * gB.w;
      c0 = p0; c1 = p1;
    }
    {
      float w0 = h2f((unsigned short)(c0 >> 16));
      float w1 = h2f((unsigned short)(c1 >> 16));
      float4 gA = ((const float4*)(G + (size_t)(c0 & 0xFFFF) * D))[lane];
      float4 gB = ((const float4*)(G + (size_t)(c1 & 0xFFFF) * D))[lane];
      ax += w0 * gA.x + w1 * gB.x;
      ay += w0 * gA.y + w1 * gB.y;
      az += w0 * gA.z + w1 * gB.z;
      aw += w0 * gA.w + w1 * gB.w;
    }
    if (j + 2 < m) {
      unsigned int e0 = csrA[s0 + j + 2];
      float w0 = h2f((unsigned short)(e0 >> 16));
      float4 gA = ((const float4*)(G + (size_t)(e0 & 0xFFFF) * D))[lane];
      ax += w0 * gA.x; ay += w0 * gA.y; az += w0 * gA.z; aw += w0 * gA.w;
    }
  } else if (m == 1) {
    unsigned int e0 = csrA[s0];
    float w0 = h2f((unsigned short)(e0 >> 16));
    float4 gA = ((const float4*)(G + (size_t)(e0 & 0xFFFF) * D))[lane];
    ax += w0 * gA.x; ay += w0 * gA.y; az += w0 * gA.z; aw += w0 * gA.w;
  }
  float4 bb = ((const float4*)b1)[lane];
  ushort4 o;
  o.x = f2bf(dn * fmaxf(dn * ax + bb.x, 0.f));
  o.y = f2bf(dn * fmaxf(dn * ay + bb.y, 0.f));
  o.z = f2bf(dn * fmaxf(dn * az + bb.z, 0.f));
  o.w = f2bf(dn * fmaxf(dn * aw + bb.w, 0.f));
  ((ushort4*)(H1 + (size_t)n * D))[lane] = o;
}

// ---- fused layer2 + pool: block = 8 contiguous nodes; per node
// v = dn*(H1p[n] + sum H1p[src]); LDS-stage; segmented atomicAdd into P ----
__global__ __launch_bounds__(256) void k_agg2pool(
    const unsigned short* __restrict__ H1, const int* __restrict__ off,
    const int* __restrict__ indeg, const float* __restrict__ dis,
    const int* __restrict__ csrB, const int* __restrict__ batch,
    float* __restrict__ P, int nn) {
  __shared__ float buf[8][D];
  __shared__ int gbuf[8];
  int t = threadIdx.x;
  int slot = t >> 5, lane = t & 31;
  int n = blockIdx.x * 8 + slot;
  float ax = 0.f, ay = 0.f, az = 0.f, aw = 0.f;
  if (n < nn) {
    float dn = dis[n];
    ushort4 u0 = ((const ushort4*)(H1 + (size_t)n * D))[lane];
    ax = bf2f(u0.x); ay = bf2f(u0.y); az = bf2f(u0.z); aw = bf2f(u0.w);
    int s0 = off[n], m = indeg[n];
    if (m >= 2) {
      int c0 = csrB[s0], c1 = csrB[s0 + 1];
      int j = 0;
      for (; j + 3 < m; j += 2) {
        int p0 = csrB[s0 + j + 2];
        int p1 = csrB[s0 + j + 3];
        ushort4 hA = ((const ushort4*)(H1 + (size_t)c0 * D))[lane];
        ushort4 hB = ((const ushort4*)(H1 + (size_t)c1 * D))[lane];
        ax += bf2f(hA.x) + bf2f(hB.x);
        ay += bf2f(hA.y) + bf2f(hB.y);
        az += bf2f(hA.z) + bf2f(hB.z);
        aw += bf2f(hA.w) + bf2f(hB.w);
        c0 = p0; c1 = p1;
      }
      {
        ushort4 hA = ((const ushort4*)(H1 + (size_t)c0 * D))[lane];
        ushort4 hB = ((const ushort4*)(H1 + (size_t)c1 * D))[lane];
        ax += bf2f(hA.x) + bf2f(hB.x);
        ay += bf2f(hA.y) + bf2f(hB.y);
        az += bf2f(hA.z) + bf2f(hB.z);
        aw += bf2f(hA.w) + bf2f(hB.w);
      }
      if (j + 2 < m) {
        int e0 = csrB[s0 + j + 2];
        ushort4 hA = ((const ushort4*)(H1 + (size_t)e0 * D))[lane];
        ax += bf2f(hA.x); ay += bf2f(hA.y); az += bf2f(hA.z); aw += bf2f(hA.w);
      }
    } else if (m == 1) {
      int e0 = csrB[s0];
      ushort4 hA = ((const ushort4*)(H1 + (size_t)e0 * D))[lane];
      ax += bf2f(hA.x); ay += bf2f(hA.y); az += bf2f(hA.z); aw += bf2f(hA.w);
    }
    ax *= dn; ay *= dn; az *= dn; aw *= dn;
  }
  ((float4*)&buf[slot][lane * 4])[0] = make_float4(ax, ay, az, aw);
  if (lane == 0) gbuf[slot] = (n < nn) ? batch[n] : -1;
  __syncthreads();
  if (t < D) {
    int c = t;
    float acc = 0.f;
    int run = -1;
    #pragma unroll
    for (int s2 = 0; s2 < 8; ++s2) {
      int g = gbuf[s2];
      if (g < 0) break;
      if (g != run) {
        if (run >= 0) atomicAdd(&P[(size_t)run * D + c], acc);
        run = g;
        acc = 0.f;
      }
      acc += buf[s2][c];
    }
    if (run >= 0) atomicAdd(&P[(size_t)run * D + c], acc);
  }
}

__global__ void k_cnt2(const int* __restrict__ batch, int* __restrict__ cnt,
                       int nn, int ng) {
  int g = blockIdx.x * blockDim.x + threadIdx.x;
  if (g >= ng) return;
  int lo = 0, hi = nn;
  while (lo < hi) { int m = (lo + hi) >> 1; if (batch[m] < g) lo = m + 1; else hi = m; }
  int s = lo;
  hi = nn;
  while (lo < hi) { int m = (lo + hi) >> 1; if (batch[m] < g + 1) lo = m + 1; else hi = m; }
  cnt[g] = lo - s;
}

__global__ void k_out_dumb(const float* __restrict__ P,
                           const int* __restrict__ cnt,
                           const float* __restrict__ W2,
                           const float* __restrict__ b2,
                           float* __restrict__ Out, int ng) {
  int idx = blockIdx.x * blockDim.x + threadIdx.x;
  if (idx >= ng * D) return;
  int g = idx >> 7, c = idx & 127;
  int m = cnt[g];
  float inv = (m > 0) ? (1.0f / (float)m) : 0.0f;
  const float* pr = P + (size_t)g * D;
  float acc = 0.f;
  for (int k = 0; k < D; ++k) acc += pr[k] * W2[k * D + c];
  acc *= inv;
  if (m > 0) acc += b2[c];
  Out[idx] = acc;
}

extern "C" void kernel_launch(void* const* d_in, const int* in_sizes, int n_in,
                              void* d_out, int out_size, void* d_ws, size_t ws_size,
                              hipStream_t stream) {
  const void* xr = d_in[0];
  const void* eir = d_in[1];
  const void* batchr = d_in[2];
  const void* emb = d_in[3];
  const void* W1 = d_in[4];
  const void* b1 = d_in[5];
  const void* W2 = d_in[6];
  const void* b2 = d_in[7];
  float* out = (float*)d_out;

  const int nn = in_sizes[0];
  const int ne = in_sizes[1] / 2;
  const int vocab = in_sizes[3] / D;
  const int ng = out_size / D;
  const int nb = (nn + 1023) / 1024;

  char* p = (char*)d_ws;
  auto alloc = [&](size_t bytes) -> char* {
    char* r = p;
    p += (bytes + 511) & ~(size_t)511;
    return r;
  };
  int* flag = (int*)alloc(512);
  int* xs = (int*)alloc((size_t)nn * 4);
  int* srcs = (int*)alloc((size_t)ne * 4);
  int* dsts = (int*)alloc((size_t)ne * 4);
  int* batchs = (int*)alloc((size_t)nn * 4);
  int* indeg = (int*)alloc((size_t)nn * 4);
  int* off = (int*)alloc((size_t)nn * 4);
  int* cursor = (int*)alloc((size_t)nn * 4);
  float* dis = (float*)alloc((size_t)nn * 4);
  int* bsum = (int*)alloc((size_t)nb * 4);
  int* cnt = (int*)alloc((size_t)ng * 4);
  unsigned int* csrA = (unsigned int*)alloc((size_t)ne * 4);
  int* csrB = (int*)alloc((size_t)ne * 4);
  float* embf = (float*)alloc((size_t)vocab * D * 4);
  float* W1f = (float*)alloc((size_t)D * D * 4);
  float* b1f = (float*)alloc((size_t)D * 4);
  float* W2f = (float*)alloc((size_t)D * D * 4);
  float* b2f = (float*)alloc((size_t)D * 4);
  float* G = (float*)alloc((size_t)vocab * D * 4);
  unsigned short* H1 = (unsigned short*)alloc((size_t)nn * D * 2);
  float* P = (float*)alloc((size_t)ng * D * 4);

  hipMemsetAsync(flag, 0, 512, stream);
  hipMemsetAsync(indeg, 0, (size_t)nn * 4, stream);
  hipMemsetAsync(P, 0, (size_t)ng * D * 4, stream);

  k_detect_f5<<<5, 256, 0, stream>>>(
      (const unsigned short*)emb, vocab * D,
      (const unsigned short*)W1, D * D,
      (const unsigned short*)b1, D,
      (const unsigned short*)W2, D * D,
      (const unsigned short*)b2, D, flag);
  k_detect_i<<<1, 64, 0, stream>>>((const unsigned int*)eir, flag + 5);

  k_conv<<<(vocab * D + 255) / 256, 256, 0, stream>>>(emb, embf, vocab * D, flag + 0);
  k_conv_params<<<(2 * D * D + 2 * D + 255) / 256, 256, 0, stream>>>(
      W1, b1, W2, b2, W1f, b1f, W2f, b2f, flag);

  {
    long long tot = 2LL * nn + 2LL * ne;
    k_convi_all<<<(int)((tot + 255) / 256), 256, 0, stream>>>(
        xr, eir, batchr, xs, srcs, dsts, batchs, indeg, nn, ne, vocab, ng, flag + 5);
  }

  k_scan1<<<nb, 1024, 0, stream>>>(indeg, off, bsum, nn);
  k_scan2<<<1, 64, 0, stream>>>(bsum, nb);
  k_scan3<<<(nn + 255) / 256, 256, 0, stream>>>(off, cursor, dis, indeg, bsum, nn);
  k_fill<<<(ne + 255) / 256, 256, 0, stream>>>(srcs, dsts, xs, dis, cursor,
                                               csrA, csrB, ne);

  k_gemm_dumb<<<(vocab * D + 255) / 256, 256, 0, stream>>>(embf, W1f, G, vocab);

  {
    long long thr = (long long)nn * 32;
    k_aggrelu<<<(int)((thr + 255) / 256), 256, 0, stream>>>(xs, G, b1f, off, indeg,
                                                            dis, csrA, H1, nn);
  }
  // fused layer2 + pool (8 nodes/block)
  k_agg2pool<<<(nn + 7) / 8, 256, 0, stream>>>(H1, off, indeg, dis, csrB,
                                               batchs, P, nn);
  k_cnt2<<<(ng + 255) / 256, 256, 0, stream>>>(batchs, cnt, nn, ng);
  k_out_dumb<<<(ng * D + 255) / 256, 256, 0, stream>>>(P, cnt, W2f, b2f, out, ng);
}

// Round 22
// 252.562 us; speedup vs baseline: 1.8275x; 1.0248x over previous
//
#include <hip/hip_runtime.h>
#include <hip/hip_bf16.h>
#include <hip/hip_fp16.h>

#define D 128

__device__ __forceinline__ float bf2f(unsigned short u) {
  return __uint_as_float(((unsigned int)u) << 16);
}
__device__ __forceinline__ unsigned short f2bf(float f) {
  unsigned int x = __float_as_uint(f);
  x += 0x7fff + ((x >> 16) & 1);
  return (unsigned short)(x >> 16);
}
__device__ __forceinline__ float h2f(unsigned short b) {
  return __half2float(__ushort_as_half(b));
}

// flags: [0..4]=float tensor is-bf16 (emb,W1,b1,W2,b2), [5]=ints-int64

__global__ void k_detect_f5(const unsigned short* __restrict__ t0, int n0,
                            const unsigned short* __restrict__ t1, int n1,
                            const unsigned short* __restrict__ t2, int n2,
                            const unsigned short* __restrict__ t3, int n3,
                            const unsigned short* __restrict__ t4, int n4,
                            int* __restrict__ flag) {
  const unsigned short* tabs[5] = {t0, t1, t2, t3, t4};
  int ns[5] = {n0, n1, n2, n3, n4};
  int b = blockIdx.x;
  const unsigned short* u16 = tabs[b];
  int n = ns[b];
  __shared__ int cnt;
  int K = n / 2 < 256 ? n / 2 : 256;
  if (threadIdx.x == 0) cnt = 0;
  __syncthreads();
  if (threadIdx.x < K) {
    unsigned short u = u16[threadIdx.x * 2];
    int e = (u >> 7) & 0xFF;
    if (u == 0 || (e >= 100 && e <= 140)) atomicAdd(&cnt, 1);
  }
  __syncthreads();
  if (threadIdx.x == 0) flag[b] = (cnt * 2 >= K) ? 1 : 0;
}

__global__ void k_detect_i(const unsigned int* __restrict__ ei32,
                           int* __restrict__ flagSlot) {
  __shared__ int z;
  if (threadIdx.x == 0) z = 0;
  __syncthreads();
  if (ei32[threadIdx.x * 2 + 1] == 0u) atomicAdd(&z, 1);
  __syncthreads();
  if (threadIdx.x == 0) *flagSlot = (z >= 60) ? 1 : 0;
}

__global__ void k_conv(const void* __restrict__ src, float* __restrict__ dst,
                       int n, const int* __restrict__ flagSlot) {
  int i = blockIdx.x * blockDim.x + threadIdx.x;
  if (i >= n) return;
  if (*flagSlot) dst[i] = bf2f(((const unsigned short*)src)[i]);
  else           dst[i] = ((const float*)src)[i];
}

__global__ void k_conv_params(const void* __restrict__ W1, const void* __restrict__ b1,
                              const void* __restrict__ W2, const void* __restrict__ b2,
                              float* __restrict__ W1f, float* __restrict__ b1f,
                              float* __restrict__ W2f, float* __restrict__ b2f,
                              const int* __restrict__ flag) {
  int i = blockIdx.x * blockDim.x + threadIdx.x;
  const int S = D * D;
  const void* src; float* dst; int j; const int* fs;
  if (i < S)                { src = W1; dst = W1f; j = i;            fs = flag + 1; }
  else if (i < S + D)       { src = b1; dst = b1f; j = i - S;        fs = flag + 2; }
  else if (i < 2 * S + D)   { src = W2; dst = W2f; j = i - S - D;    fs = flag + 3; }
  else if (i < 2 * S + 2*D) { src = b2; dst = b2f; j = i - 2*S - D;  fs = flag + 4; }
  else return;
  if (*fs) dst[j] = bf2f(((const unsigned short*)src)[j]);
  else     dst[j] = ((const float*)src)[j];
}

// fused int conversion; dst branch also counts in-degrees (indeg pre-zeroed)
__global__ void k_convi_all(const void* __restrict__ xr, const void* __restrict__ eir,
                            const void* __restrict__ br,
                            int* __restrict__ xs, int* __restrict__ srcs,
                            int* __restrict__ dsts, int* __restrict__ batchs,
                            int* __restrict__ indeg,
                            int nn, int ne, int vocab, int ng,
                            const int* __restrict__ flag64) {
  long long i = (long long)blockIdx.x * blockDim.x + threadIdx.x;
  int is64 = *flag64;
  if (i < nn) {
    int v = is64 ? (int)((const long long*)xr)[i] : ((const int*)xr)[i];
    v = v < 0 ? 0 : (v > vocab - 1 ? vocab - 1 : v);
    xs[i] = v;
  } else if (i < (long long)nn + ne) {
    long long j = i - nn;
    int v = is64 ? (int)((const long long*)eir)[j] : ((const int*)eir)[j];
    v = v < 0 ? 0 : (v > nn - 1 ? nn - 1 : v);
    srcs[j] = v;
  } else if (i < (long long)nn + 2 * ne) {
    long long j = i - nn - ne;
    int v = is64 ? (int)((const long long*)eir)[ne + j] : ((const int*)eir)[ne + j];
    v = v < 0 ? 0 : (v > nn - 1 ? nn - 1 : v);
    dsts[j] = v;
    atomicAdd(&indeg[v], 1);
  } else if (i < 2LL * nn + 2 * ne) {
    long long j = i - nn - 2 * ne;
    int v = is64 ? (int)((const long long*)br)[j] : ((const int*)br)[j];
    v = v < 0 ? 0 : (v > ng - 1 ? ng - 1 : v);
    batchs[j] = v;
  }
}

// ---------------- CSR scan -------------------------------------------------
__global__ __launch_bounds__(1024) void k_scan1(const int* __restrict__ indeg,
                                                int* __restrict__ off,
                                                int* __restrict__ bsum, int nn) {
  int t = threadIdx.x;
  int idx = blockIdx.x * 1024 + t;
  int v = (idx < nn) ? indeg[idx] : 0;
  int lane = t & 63, wid = t >> 6;
  int inc = v;
  #pragma unroll
  for (int d = 1; d < 64; d <<= 1) {
    int u = __shfl_up(inc, d);
    if (lane >= d) inc += u;
  }
  __shared__ int ws[16];
  if (lane == 63) ws[wid] = inc;
  __syncthreads();
  if (wid == 0) {
    int wv = (lane < 16) ? ws[lane] : 0;
    #pragma unroll
    for (int d = 1; d < 16; d <<= 1) {
      int u = __shfl_up(wv, d);
      if (lane >= d) wv += u;
    }
    if (lane < 16) ws[lane] = wv;
  }
  __syncthreads();
  int base = wid ? ws[wid - 1] : 0;
  if (idx < nn) off[idx] = base + inc - v;
  if (t == 1023) bsum[blockIdx.x] = ws[15];
}

__global__ void k_scan2(int* __restrict__ bsum, int nb) {
  if (blockIdx.x == 0 && threadIdx.x == 0) {
    int run = 0;
    for (int i = 0; i < nb; ++i) { int s = bsum[i]; bsum[i] = run; run += s; }
  }
}

__global__ void k_scan3(int* __restrict__ off, int* __restrict__ cursor,
                        float* __restrict__ dis, const int* __restrict__ indeg,
                        const int* __restrict__ bsum, int nn) {
  int idx = blockIdx.x * blockDim.x + threadIdx.x;
  if (idx >= nn) return;
  int o = off[idx] + bsum[idx >> 10];
  off[idx] = o;
  cursor[idx] = o;
  dis[idx] = rsqrtf((float)indeg[idx] + 1.0f);  // +1 self-loop
}

// fill unified CSR: csr[pp] = { src, x[src] | f16(dis[src])<<16 }
// single 8 B scatter per edge (one cache line instead of two)
__global__ void k_fill(const int* __restrict__ srcA, const int* __restrict__ dstA,
                       const int* __restrict__ xs, const float* __restrict__ dis,
                       int* __restrict__ cursor, int2* __restrict__ csr, int ne) {
  int e = blockIdx.x * blockDim.x + threadIdx.x;
  if (e >= ne) return;
  int d = dstA[e], s = srcA[e];
  unsigned short hb = __half_as_ushort(__float2half_rn(dis[s]));
  unsigned int packed = (unsigned int)xs[s] | ((unsigned int)hb << 16);
  int pp = atomicAdd(&cursor[d], 1);
  csr[pp] = make_int2(s, (int)packed);
}

// ---------------- G = emb @ W1 --------------------------------------------
__global__ void k_gemm_dumb(const float* __restrict__ A,
                            const float* __restrict__ W,
                            float* __restrict__ OUT, int rows) {
  int idx = blockIdx.x * blockDim.x + threadIdx.x;
  if (idx >= rows * D) return;
  int r = idx >> 7, c = idx & 127;
  const float* a = A + (size_t)r * D;
  float acc = 0.f;
  for (int k = 0; k < D; ++k) acc += a[k] * W[k * D + c];
  OUT[idx] = acc;
}

// ---- layer1: H1p[n] = dn * relu(dn*(dn*G[x[n]] + sum dis_s*G[x_s]) + b1) -
// 32 lanes/node, software-pipelined, unified 8 B csr entries (uses .y)
__global__ __launch_bounds__(256) void k_aggrelu(const int* __restrict__ x,
                                                 const float* __restrict__ G,
                                                 const float* __restrict__ b1,
                                                 const int* __restrict__ off,
                                                 const int* __restrict__ indeg,
                                                 const float* __restrict__ dis,
                                                 const int2* __restrict__ csr,
                                                 unsigned short* __restrict__ H1,
                                                 int nn) {
  int gid = blockIdx.x * blockDim.x + threadIdx.x;
  int n = gid >> 5;
  if (n >= nn) return;
  int lane = threadIdx.x & 31;
  float dn = dis[n];
  float4 g0 = ((const float4*)(G + (size_t)x[n] * D))[lane];
  float ax = dn * g0.x, ay = dn * g0.y, az = dn * g0.z, aw = dn * g0.w;
  int s0 = off[n], m = indeg[n];
  if (m >= 2) {
    unsigned int c0 = (unsigned int)csr[s0].y, c1 = (unsigned int)csr[s0 + 1].y;
    int j = 0;
    for (; j + 3 < m; j += 2) {
      unsigned int p0 = (unsigned int)csr[s0 + j + 2].y;
      unsigned int p1 = (unsigned int)csr[s0 + j + 3].y;
      float w0 = h2f((unsigned short)(c0 >> 16));
      float w1 = h2f((unsigned short)(c1 >> 16));
      float4 gA = ((const float4*)(G + (size_t)(c0 & 0xFFFF) * D))[lane];
      float4 gB = ((const float4*)(G + (size_t)(c1 & 0xFFFF) * D))[lane];
      ax += w0 * gA.x + w1 * gB.x;
      ay += w0 * gA.y + w1 * gB.y;
      az += w0 * gA.z + w1 * gB.z;
      aw += w0 * gA.w + w1 * gB.w;
      c0 = p0; c1 = p1;
    }
    {
      float w0 = h2f((unsigned short)(c0 >> 16));
      float w1 = h2f((unsigned short)(c1 >> 16));
      float4 gA = ((const float4*)(G + (size_t)(c0 & 0xFFFF) * D))[lane];
      float4 gB = ((const float4*)(G + (size_t)(c1 & 0xFFFF) * D))[lane];
      ax += w0 * gA.x + w1 * gB.x;
      ay += w0 * gA.y + w1 * gB.y;
      az += w0 * gA.z + w1 * gB.z;
      aw += w0 * gA.w + w1 * gB.w;
    }
    if (j + 2 < m) {
      unsigned int e0 = (unsigned int)csr[s0 + j + 2].y;
      float w0 = h2f((unsigned short)(e0 >> 16));
      float4 gA = ((const float4*)(G + (size_t)(e0 & 0xFFFF) * D))[lane];
      ax += w0 * gA.x; ay += w0 * gA.y; az += w0 * gA.z; aw += w0 * gA.w;
    }
  } else if (m == 1) {
    unsigned int e0 = (unsigned int)csr[s0].y;
    float w0 = h2f((unsigned short)(e0 >> 16));
    float4 gA = ((const float4*)(G + (size_t)(e0 & 0xFFFF) * D))[lane];
    ax += w0 * gA.x; ay += w0 * gA.y; az += w0 * gA.z; aw += w0 * gA.w;
  }
  float4 bb = ((const float4*)b1)[lane];
  ushort4 o;
  o.x = f2bf(dn * fmaxf(dn * ax + bb.x, 0.f));
  o.y = f2bf(dn * fmaxf(dn * ay + bb.y, 0.f));
  o.z = f2bf(dn * fmaxf(dn * az + bb.z, 0.f));
  o.w = f2bf(dn * fmaxf(dn * aw + bb.w, 0.f));
  ((ushort4*)(H1 + (size_t)n * D))[lane] = o;
}

// ---- fused layer2 + pool: block = 8 contiguous nodes; per node
// v = dn*(H1p[n] + sum H1p[src]); LDS-stage; segmented atomicAdd into P ----
__global__ __launch_bounds__(256) void k_agg2pool(
    const unsigned short* __restrict__ H1, const int* __restrict__ off,
    const int* __restrict__ indeg, const float* __restrict__ dis,
    const int2* __restrict__ csr, const int* __restrict__ batch,
    float* __restrict__ P, int nn) {
  __shared__ float buf[8][D];
  __shared__ int gbuf[8];
  int t = threadIdx.x;
  int slot = t >> 5, lane = t & 31;
  int n = blockIdx.x * 8 + slot;
  float ax = 0.f, ay = 0.f, az = 0.f, aw = 0.f;
  if (n < nn) {
    float dn = dis[n];
    ushort4 u0 = ((const ushort4*)(H1 + (size_t)n * D))[lane];
    ax = bf2f(u0.x); ay = bf2f(u0.y); az = bf2f(u0.z); aw = bf2f(u0.w);
    int s0 = off[n], m = indeg[n];
    if (m >= 2) {
      int c0 = csr[s0].x, c1 = csr[s0 + 1].x;
      int j = 0;
      for (; j + 3 < m; j += 2) {
        int p0 = csr[s0 + j + 2].x;
        int p1 = csr[s0 + j + 3].x;
        ushort4 hA = ((const ushort4*)(H1 + (size_t)c0 * D))[lane];
        ushort4 hB = ((const ushort4*)(H1 + (size_t)c1 * D))[lane];
        ax += bf2f(hA.x) + bf2f(hB.x);
        ay += bf2f(hA.y) + bf2f(hB.y);
        az += bf2f(hA.z) + bf2f(hB.z);
        aw += bf2f(hA.w) + bf2f(hB.w);
        c0 = p0; c1 = p1;
      }
      {
        ushort4 hA = ((const ushort4*)(H1 + (size_t)c0 * D))[lane];
        ushort4 hB = ((const ushort4*)(H1 + (size_t)c1 * D))[lane];
        ax += bf2f(hA.x) + bf2f(hB.x);
        ay += bf2f(hA.y) + bf2f(hB.y);
        az += bf2f(hA.z) + bf2f(hB.z);
        aw += bf2f(hA.w) + bf2f(hB.w);
      }
      if (j + 2 < m) {
        int e0 = csr[s0 + j + 2].x;
        ushort4 hA = ((const ushort4*)(H1 + (size_t)e0 * D))[lane];
        ax += bf2f(hA.x); ay += bf2f(hA.y); az += bf2f(hA.z); aw += bf2f(hA.w);
      }
    } else if (m == 1) {
      int e0 = csr[s0].x;
      ushort4 hA = ((const ushort4*)(H1 + (size_t)e0 * D))[lane];
      ax += bf2f(hA.x); ay += bf2f(hA.y); az += bf2f(hA.z); aw += bf2f(hA.w);
    }
    ax *= dn; ay *= dn; az *= dn; aw *= dn;
  }
  ((float4*)&buf[slot][lane * 4])[0] = make_float4(ax, ay, az, aw);
  if (lane == 0) gbuf[slot] = (n < nn) ? batch[n] : -1;
  __syncthreads();
  if (t < D) {
    int c = t;
    float acc = 0.f;
    int run = -1;
    #pragma unroll
    for (int s2 = 0; s2 < 8; ++s2) {
      int g = gbuf[s2];
      if (g < 0) break;
      if (g != run) {
        if (run >= 0) atomicAdd(&P[(size_t)run * D + c], acc);
        run = g;
        acc = 0.f;
      }
      acc += buf[s2][c];
    }
    if (run >= 0) atomicAdd(&P[(size_t)run * D + c], acc);
  }
}

__global__ void k_cnt2(const int* __restrict__ batch, int* __restrict__ cnt,
                       int nn, int ng) {
  int g = blockIdx.x * blockDim.x + threadIdx.x;
  if (g >= ng) return;
  int lo = 0, hi = nn;
  while (lo < hi) { int m = (lo + hi) >> 1; if (batch[m] < g) lo = m + 1; else hi = m; }
  int s = lo;
  hi = nn;
  while (lo < hi) { int m = (lo + hi) >> 1; if (batch[m] < g + 1) lo = m + 1; else hi = m; }
  cnt[g] = lo - s;
}

__global__ void k_out_dumb(const float* __restrict__ P,
                           const int* __restrict__ cnt,
                           const float* __restrict__ W2,
                           const float* __restrict__ b2,
                           float* __restrict__ Out, int ng) {
  int idx = blockIdx.x * blockDim.x + threadIdx.x;
  if (idx >= ng * D) return;
  int g = idx >> 7, c = idx & 127;
  int m = cnt[g];
  float inv = (m > 0) ? (1.0f / (float)m) : 0.0f;
  const float* pr = P + (size_t)g * D;
  float acc = 0.f;
  for (int k = 0; k < D; ++k) acc += pr[k] * W2[k * D + c];
  acc *= inv;
  if (m > 0) acc += b2[c];
  Out[idx] = acc;
}

extern "C" void kernel_launch(void* const* d_in, const int* in_sizes, int n_in,
                              void* d_out, int out_size, void* d_ws, size_t ws_size,
                              hipStream_t stream) {
  const void* xr = d_in[0];
  const void* eir = d_in[1];
  const void* batchr = d_in[2];
  const void* emb = d_in[3];
  const void* W1 = d_in[4];
  const void* b1 = d_in[5];
  const void* W2 = d_in[6];
  const void* b2 = d_in[7];
  float* out = (float*)d_out;

  const int nn = in_sizes[0];
  const int ne = in_sizes[1] / 2;
  const int vocab = in_sizes[3] / D;
  const int ng = out_size / D;
  const int nb = (nn + 1023) / 1024;

  char* p = (char*)d_ws;
  auto alloc = [&](size_t bytes) -> char* {
    char* r = p;
    p += (bytes + 511) & ~(size_t)511;
    return r;
  };
  int* flag = (int*)alloc(512);
  int* xs = (int*)alloc((size_t)nn * 4);
  int* srcs = (int*)alloc((size_t)ne * 4);
  int* dsts = (int*)alloc((size_t)ne * 4);
  int* batchs = (int*)alloc((size_t)nn * 4);
  int* indeg = (int*)alloc((size_t)nn * 4);
  int* off = (int*)alloc((size_t)nn * 4);
  int* cursor = (int*)alloc((size_t)nn * 4);
  float* dis = (float*)alloc((size_t)nn * 4);
  int* bsum = (int*)alloc((size_t)nb * 4);
  int* cnt = (int*)alloc((size_t)ng * 4);
  int2* csr = (int2*)alloc((size_t)ne * 8);
  float* embf = (float*)alloc((size_t)vocab * D * 4);
  float* W1f = (float*)alloc((size_t)D * D * 4);
  float* b1f = (float*)alloc((size_t)D * 4);
  float* W2f = (float*)alloc((size_t)D * D * 4);
  float* b2f = (float*)alloc((size_t)D * 4);
  float* G = (float*)alloc((size_t)vocab * D * 4);
  unsigned short* H1 = (unsigned short*)alloc((size_t)nn * D * 2);
  float* P = (float*)alloc((size_t)ng * D * 4);

  hipMemsetAsync(flag, 0, 512, stream);
  hipMemsetAsync(indeg, 0, (size_t)nn * 4, stream);
  hipMemsetAsync(P, 0, (size_t)ng * D * 4, stream);

  k_detect_f5<<<5, 256, 0, stream>>>(
      (const unsigned short*)emb, vocab * D,
      (const unsigned short*)W1, D * D,
      (const unsigned short*)b1, D,
      (const unsigned short*)W2, D * D,
      (const unsigned short*)b2, D, flag);
  k_detect_i<<<1, 64, 0, stream>>>((const unsigned int*)eir, flag + 5);

  k_conv<<<(vocab * D + 255) / 256, 256, 0, stream>>>(emb, embf, vocab * D, flag + 0);
  k_conv_params<<<(2 * D * D + 2 * D + 255) / 256, 256, 0, stream>>>(
      W1, b1, W2, b2, W1f, b1f, W2f, b2f, flag);

  {
    long long tot = 2LL * nn + 2LL * ne;
    k_convi_all<<<(int)((tot + 255) / 256), 256, 0, stream>>>(
        xr, eir, batchr, xs, srcs, dsts, batchs, indeg, nn, ne, vocab, ng, flag + 5);
  }

  k_scan1<<<nb, 1024, 0, stream>>>(indeg, off, bsum, nn);
  k_scan2<<<1, 64, 0, stream>>>(bsum, nb);
  k_scan3<<<(nn + 255) / 256, 256, 0, stream>>>(off, cursor, dis, indeg, bsum, nn);
  k_fill<<<(ne + 255) / 256, 256, 0, stream>>>(srcs, dsts, xs, dis, cursor, csr, ne);

  k_gemm_dumb<<<(vocab * D + 255) / 256, 256, 0, stream>>>(embf, W1f, G, vocab);

  {
    long long thr = (long long)nn * 32;
    k_aggrelu<<<(int)((thr + 255) / 256), 256, 0, stream>>>(xs, G, b1f, off, indeg,
                                                            dis, csr, H1, nn);
  }
  k_agg2pool<<<(nn + 7) / 8, 256, 0, stream>>>(H1, off, indeg, dis, csr,
                                               batchs, P, nn);
  k_cnt2<<<(ng + 255) / 256, 256, 0, stream>>>(batchs, cnt, nn, ng);
  k_out_dumb<<<(ng * D + 255) / 256, 256, 0, stream>>>(P, cnt, W2f, b2f, out, ng);
}